// Round 14
// baseline (833.656 us; speedup 1.0000x reference)
//
#include <hip/hip_runtime.h>
#include <hip/hip_bf16.h>
#include <stdint.h>

// B=512 L=32 E=2048 H=32 D=64 ; M = B*L = 16384 ; K = 2048 ; Nqkv = 6144
typedef __bf16 bf16x8 __attribute__((ext_vector_type(8)));
typedef float f32x4 __attribute__((ext_vector_type(4)));
typedef unsigned short u16x8 __attribute__((ext_vector_type(8)));
typedef unsigned short u16x4 __attribute__((ext_vector_type(4)));

#define G_AS __attribute__((address_space(1)))
#define L_AS __attribute__((address_space(3)))

__device__ __forceinline__ void gload_lds16(const void* g, void* l) {
  __builtin_amdgcn_global_load_lds((G_AS void*)g, (L_AS void*)l, 16, 0, 0);
}

__device__ __forceinline__ float b2f(unsigned short u) {
  union { float f; unsigned int i; } cv;
  cv.i = ((unsigned int)u) << 16;
  return cv.f;
}

__device__ __forceinline__ unsigned short f2b(float f) {
  unsigned int u = __float_as_uint(f);
  unsigned int r = u + 0x7FFFu + ((u >> 16) & 1u);  // RNE (inputs are non-NaN)
  return (unsigned short)(r >> 16);
}

// ---------------- cast / pack kernels ----------------

__global__ void k_cast_f32_bf16(const float* __restrict__ src,
                                unsigned short* __restrict__ dst, int n4) {
  int i = blockIdx.x * blockDim.x + threadIdx.x;
  if (i >= n4) return;
  float4 v = reinterpret_cast<const float4*>(src)[i];
  u16x4 o;
  o[0] = f2b(v.x); o[1] = f2b(v.y); o[2] = f2b(v.z); o[3] = f2b(v.w);
  reinterpret_cast<u16x4*>(dst)[i] = o;
}

// wqkvb rows: [0,2048)=wq, [2048,4096)=wk*0.125 (folds softmax scale), [4096,6144)=wv
__global__ void k_build_wqkv(const float* __restrict__ wq, const float* __restrict__ wk,
                             const float* __restrict__ wv, unsigned short* __restrict__ dst) {
  int i = blockIdx.x * blockDim.x + threadIdx.x;  // 6144*2048/4 = 3145728 threads
  if (i >= 3145728) return;
  int e = i << 2;
  int row = e >> 11;
  int col = e & 2047;
  const float* src; float sc = 1.0f;
  if (row < 2048) { src = wq + ((size_t)row << 11); }
  else if (row < 4096) { src = wk + ((size_t)(row - 2048) << 11); sc = 0.125f; }
  else { src = wv + ((size_t)(row - 4096) << 11); }
  float4 v = *reinterpret_cast<const float4*>(src + col);
  u16x4 o;
  o[0] = f2b(v.x * sc); o[1] = f2b(v.y * sc); o[2] = f2b(v.z * sc); o[3] = f2b(v.w * sc);
  *reinterpret_cast<u16x4*>(dst + e) = o;
}

__global__ void k_build_bqkv(const float* __restrict__ bq, const float* __restrict__ bk,
                             const float* __restrict__ bv, float* __restrict__ dst) {
  int i = blockIdx.x * blockDim.x + threadIdx.x;
  if (i >= 6144) return;
  float v;
  if (i < 2048) v = bq[i];
  else if (i < 4096) v = bk[i - 2048] * 0.125f;
  else v = bv[i - 4096];
  dst[i] = v;
}

// relb[h][j][d] = rpe[h - j + 31][d]   (faithful to the reference's H==L broadcast quirk)
__global__ void k_build_rel(const float* __restrict__ rpe, unsigned short* __restrict__ dst) {
  int i = blockIdx.x * blockDim.x + threadIdx.x;  // 32*32*16 = 16384
  if (i >= 16384) return;
  int h = i >> 9;
  int j = (i >> 4) & 31;
  int d = (i & 15) << 2;
  const float* s = rpe + (size_t)(h - j + 31) * 64 + d;
  float4 v = *reinterpret_cast<const float4*>(s);
  u16x4 o;
  o[0] = f2b(v.x); o[1] = f2b(v.y); o[2] = f2b(v.z); o[3] = f2b(v.w);
  *reinterpret_cast<u16x4*>(dst + ((size_t)i << 2)) = o;
}

// ---------------- GEMM: C[M][N] = A[M][K] * B[N][K]^T + bias[N] ----------------
// Round-8 winner (472 us QKV, 873 TF) with ONE change: staging lookahead 2 -> 3
// tiles (3-buf -> 4-buf ring, 96 -> 128 KiB; occupancy already 1 block/CU so no
// occupancy change). Issue-to-wait distance ~1300 cyc >= ~900 cyc HBM latency.
//
// Per K-tile t (2 fine phases, round-8 shape preserved):
//  ph0: { reads bf(4)+afL(4) of buf t&3 (valid since iter t-1's wait+barrier);
//         stage A(t+3) } BAR ; 16 MFMA ; BAR
//  ph1: { reads afH(4); stage B(t+3); vmcnt(8) } BAR ; 16 MFMA ; BAR
// vmcnt ledger at ph1: outstanding = tiles t+1,t+2 (8) + own t+3 (4) = 12;
//   vmcnt(8) completes t+1 exactly. Tail: 8 -> 4 -> 0.
// WAR: stage into buf (t+3)&3 = buf (t-1)&3; A(t-1)/B(t-1) reads completed
//   before their MFMA (lgkm) which precedes >=2 barriers before iter t. OK.
//
// XOR-swizzled LDS layout (round-8, proven): row-major [256][32] ushort per buf,
// slot' = s ^ ((row>>1)&3); staging keeps 64B-line coalescing; ds_read slot =
// q ^ ((fr>>1)&3) -> conflict-free (0 measured).

template <int OUT_F32>
__global__ __launch_bounds__(512, 1)
void k_gemm256(const unsigned short* __restrict__ A,
               const unsigned short* __restrict__ B,
               const float* __restrict__ bias,
               void* __restrict__ Cptr,
               int M, int N, int K)
{
  __shared__ __align__(16) unsigned short As[4][8192];
  __shared__ __align__(16) unsigned short Bs[4][8192];

  // bijective XCD swizzle, bm-major
  const int nbn = N >> 8;
  const int cpx = gridDim.x >> 3;
  const int orig = blockIdx.x;
  const int wg = (orig & 7) * cpx + (orig >> 3);
  const int bm = wg / nbn;
  const int bn = wg % nbn;

  const int tid = threadIdx.x;
  const int lane = tid & 63;
  const int wid = tid >> 6;
  const int wr = wid >> 2;   // 0..1  (m-half)
  const int wc = wid & 3;    // 0..3  (64-col strip)

  // staging: chunk c=tid -> row tid>>2 (0..127), chunk c+512 -> row+128.
  const int rs = tid >> 2;
  const int cs = ((tid & 3) ^ ((tid >> 3) & 3)) << 3;
  const unsigned short* agA0 = A + (size_t)(bm * 256 + rs) * K + cs;
  const unsigned short* agA1 = agA0 + (size_t)128 * K;
  const unsigned short* agB0 = B + (size_t)(bn * 256 + rs) * K + cs;
  const unsigned short* agB1 = agB0 + (size_t)128 * K;
  const int ldst = tid * 8;

  // fragment read offsets (ushort index inside one 8192-ushort matrix-buf)
  const int fr = lane & 15;
  const int q  = lane >> 4;                       // k-slot 0..3
  const int sx = q ^ ((fr >> 1) & 3);             // swizzled slot (lane constant)
  const int rbase = fr * 32 + sx * 8;
  const int aOff = wr * 4096 + rbase;             // + m*512, m=0..7
  const int bOff = wc * 2048 + rbase;             // + n*512, n=0..3

  f32x4 acc[8][4] = {};
  const int NT = K >> 5;   // 64 K-tiles

  // prologue: stage tiles 0,1,2 into bufs 0,1,2
#pragma unroll
  for (int pf = 0; pf < 3; ++pf) {
    const int kof = pf << 5;
    gload_lds16(agA0 + kof, &As[pf][ldst]);
    gload_lds16(agA1 + kof, &As[pf][ldst + 4096]);
    gload_lds16(agB0 + kof, &Bs[pf][ldst]);
    gload_lds16(agB1 + kof, &Bs[pf][ldst + 4096]);
  }
  asm volatile("s_waitcnt vmcnt(8)" ::: "memory");   // tile 0 landed
  asm volatile("s_barrier" ::: "memory");

  for (int t = 0; t < NT; ++t) {
    const int rb = t & 3;
    const int sb = (t + 3) & 3;
    const unsigned short* ab = &As[rb][0];
    const unsigned short* bb = &Bs[rb][0];
    const bool st = (t + 3) < NT;               // uniform
    const int kof = (t + 3) << 5;

    // ===== phase 0: bf + afL reads (valid buf), stage A(t+3) =====
    bf16x8 afL[4], bf[4];
#pragma unroll
    for (int n = 0; n < 4; ++n)
      bf[n] = *reinterpret_cast<const bf16x8*>(bb + bOff + n * 512);
#pragma unroll
    for (int m = 0; m < 4; ++m)
      afL[m] = *reinterpret_cast<const bf16x8*>(ab + aOff + m * 512);
    if (st) {
      gload_lds16(agA0 + kof, &As[sb][ldst]);
      gload_lds16(agA1 + kof, &As[sb][ldst + 4096]);
    }
    __builtin_amdgcn_sched_barrier(0);
    asm volatile("s_barrier" ::: "memory");
    __builtin_amdgcn_sched_barrier(0);
    __builtin_amdgcn_s_setprio(1);
#pragma unroll
    for (int m = 0; m < 4; ++m)
#pragma unroll
      for (int n = 0; n < 4; ++n)
        acc[m][n] = __builtin_amdgcn_mfma_f32_16x16x32_bf16(afL[m], bf[n], acc[m][n], 0, 0, 0);
    __builtin_amdgcn_s_setprio(0);
    __builtin_amdgcn_sched_barrier(0);
    asm volatile("s_barrier" ::: "memory");

    // ===== phase 1: afH reads, stage B(t+3), counted wait =====
    bf16x8 afH[4];
#pragma unroll
    for (int m = 0; m < 4; ++m)
      afH[m] = *reinterpret_cast<const bf16x8*>(ab + aOff + (4 + m) * 512);
    if (st) {
      gload_lds16(agB0 + kof, &Bs[sb][ldst]);
      gload_lds16(agB1 + kof, &Bs[sb][ldst + 4096]);
    }
    if (st)                  asm volatile("s_waitcnt vmcnt(8)" ::: "memory");
    else if (t + 2 < NT)     asm volatile("s_waitcnt vmcnt(4)" ::: "memory");
    else if (t + 1 < NT)     asm volatile("s_waitcnt vmcnt(0)" ::: "memory");
    __builtin_amdgcn_sched_barrier(0);
    asm volatile("s_barrier" ::: "memory");
    __builtin_amdgcn_sched_barrier(0);
    __builtin_amdgcn_s_setprio(1);
#pragma unroll
    for (int m = 0; m < 4; ++m)
#pragma unroll
      for (int n = 0; n < 4; ++n)
        acc[4 + m][n] = __builtin_amdgcn_mfma_f32_16x16x32_bf16(afH[m], bf[n], acc[4 + m][n], 0, 0, 0);
    __builtin_amdgcn_s_setprio(0);
    __builtin_amdgcn_sched_barrier(0);
    asm volatile("s_barrier" ::: "memory");
  }

  // epilogue: C/D layout col = lane&15, row = (lane>>4)*4 + reg
  const int rBase = bm * 256 + wr * 128 + (q << 2);
  const int cBase = bn * 256 + wc * 64 + fr;
#pragma unroll
  for (int n = 0; n < 4; ++n) {
    const int col = cBase + n * 16;
    const float bv = bias[col];
#pragma unroll
    for (int m = 0; m < 8; ++m) {
      const int row = rBase + m * 16;
#pragma unroll
      for (int r = 0; r < 4; ++r) {
        float v = acc[m][n][r] + bv;
        if (OUT_F32) {
          reinterpret_cast<float*>(Cptr)[(size_t)(row + r) * N + col] = v;
        } else {
          reinterpret_cast<unsigned short*>(Cptr)[(size_t)(row + r) * N + col] = f2b(v);
        }
      }
    }
  }
}

// ---------------- attention: one block (256 thr) per (b,h) ----------------
// Round-14 deltas: (a) in-register softmax (shfl_xor over the 8-thread row
// group replaces two 32-iter LDS loops + 2 barriers); (b) LDS stride 68 -> 66
// words (QK k-row reads drop from 4-way to 2-way bank aliasing);
// (c) 1/den folded into P before the broadcast write (saves epilogue mul).

__global__ __launch_bounds__(256)
void k_attn(const unsigned short* __restrict__ qkv,
            const unsigned short* __restrict__ relb,
            unsigned short* __restrict__ ctx)
{
  __shared__ float qL[32][66];
  __shared__ float krL[32][66];
  __shared__ float vL[32][66];
  __shared__ float PL[32][33];

  const int bh = blockIdx.x;
  const int b = bh >> 5;
  const int h = bh & 31;
  const int t = threadIdx.x;
  const int r = t >> 3;           // row 0..31
  const int d0 = (t & 7) << 3;    // d 0..56 step 8

  const unsigned short* base = qkv + (size_t)(b * 32 + r) * 6144 + h * 64 + d0;
  u16x8 uq = *reinterpret_cast<const u16x8*>(base);
  u16x8 uk = *reinterpret_cast<const u16x8*>(base + 2048);
  u16x8 uv = *reinterpret_cast<const u16x8*>(base + 4096);
  u16x8 ur = *reinterpret_cast<const u16x8*>(relb + (((size_t)(h * 32 + r)) << 6) + d0);

  float fq[8], fkr[8], fv[8];
#pragma unroll
  for (int c = 0; c < 8; ++c) {
    fq[c] = b2f(uq[c]);
    fkr[c] = b2f(uk[c]) + b2f(ur[c]);
    fv[c] = b2f(uv[c]);
  }
  *reinterpret_cast<float4*>(&qL[r][d0])      = make_float4(fq[0], fq[1], fq[2], fq[3]);
  *reinterpret_cast<float4*>(&qL[r][d0 + 4])  = make_float4(fq[4], fq[5], fq[6], fq[7]);
  *reinterpret_cast<float4*>(&krL[r][d0])     = make_float4(fkr[0], fkr[1], fkr[2], fkr[3]);
  *reinterpret_cast<float4*>(&krL[r][d0 + 4]) = make_float4(fkr[4], fkr[5], fkr[6], fkr[7]);
  *reinterpret_cast<float4*>(&vL[r][d0])      = make_float4(fv[0], fv[1], fv[2], fv[3]);
  *reinterpret_cast<float4*>(&vL[r][d0 + 4])  = make_float4(fv[4], fv[5], fv[6], fv[7]);
  __syncthreads();

  const int i = r;
  const int j0 = (t & 7) << 2;   // 4 score cols per thread
  float s0 = 0.f, s1 = 0.f, s2 = 0.f, s3 = 0.f;
#pragma unroll
  for (int d = 0; d < 64; d += 4) {
    float4 qv = *reinterpret_cast<const float4*>(&qL[i][d]);
    float4 k0 = *reinterpret_cast<const float4*>(&krL[j0 + 0][d]);
    float4 k1 = *reinterpret_cast<const float4*>(&krL[j0 + 1][d]);
    float4 k2 = *reinterpret_cast<const float4*>(&krL[j0 + 2][d]);
    float4 k3 = *reinterpret_cast<const float4*>(&krL[j0 + 3][d]);
    s0 += qv.x * k0.x + qv.y * k0.y + qv.z * k0.z + qv.w * k0.w;
    s1 += qv.x * k1.x + qv.y * k1.y + qv.z * k1.z + qv.w * k1.w;
    s2 += qv.x * k2.x + qv.y * k2.y + qv.z * k2.z + qv.w * k2.w;
    s3 += qv.x * k3.x + qv.y * k3.y + qv.z * k3.z + qv.w * k3.w;
  }

  // in-register softmax over the row (8 threads x 4 values; group never
  // crosses a wave: rows are 8 consecutive lanes)
  float mx = fmaxf(fmaxf(s0, s1), fmaxf(s2, s3));
  mx = fmaxf(mx, __shfl_xor(mx, 1));
  mx = fmaxf(mx, __shfl_xor(mx, 2));
  mx = fmaxf(mx, __shfl_xor(mx, 4));
  float p0 = __expf(s0 - mx), p1 = __expf(s1 - mx), p2 = __expf(s2 - mx), p3 = __expf(s3 - mx);
  float sm = p0 + p1 + p2 + p3;
  sm += __shfl_xor(sm, 1);
  sm += __shfl_xor(sm, 2);
  sm += __shfl_xor(sm, 4);
  const float inv = 1.0f / sm;
  PL[i][j0 + 0] = p0 * inv; PL[i][j0 + 1] = p1 * inv;
  PL[i][j0 + 2] = p2 * inv; PL[i][j0 + 3] = p3 * inv;
  __syncthreads();

  float o[8] = {0.f, 0.f, 0.f, 0.f, 0.f, 0.f, 0.f, 0.f};
#pragma unroll
  for (int jj = 0; jj < 32; ++jj) {
    float pj = PL[i][jj];
    float4 v0 = *reinterpret_cast<const float4*>(&vL[jj][d0]);
    float4 v1 = *reinterpret_cast<const float4*>(&vL[jj][d0 + 4]);
    o[0] += pj * v0.x; o[1] += pj * v0.y; o[2] += pj * v0.z; o[3] += pj * v0.w;
    o[4] += pj * v1.x; o[5] += pj * v1.y; o[6] += pj * v1.z; o[7] += pj * v1.w;
  }
  u16x8 ov;
#pragma unroll
  for (int c = 0; c < 8; ++c) ov[c] = f2b(o[c]);
  *reinterpret_cast<u16x8*>(ctx + (size_t)(b * 32 + i) * 2048 + h * 64 + d0) = ov;
}

// ---------------- launch ----------------

extern "C" void kernel_launch(void* const* d_in, const int* in_sizes, int n_in,
                              void* d_out, int out_size, void* d_ws, size_t ws_size,
                              hipStream_t stream) {
  const float* x   = (const float*)d_in[0];
  const float* wq  = (const float*)d_in[1];
  const float* bq  = (const float*)d_in[2];
  const float* wk  = (const float*)d_in[3];
  const float* bk  = (const float*)d_in[4];
  const float* wv  = (const float*)d_in[5];
  const float* bv  = (const float*)d_in[6];
  const float* wo  = (const float*)d_in[7];
  const float* bo  = (const float*)d_in[8];
  const float* rpe = (const float*)d_in[9];

  char* ws = (char*)d_ws;
  unsigned short* xb    = (unsigned short*)(ws);
  unsigned short* wqkvb = (unsigned short*)(ws + 67108864);
  unsigned short* wob   = (unsigned short*)(ws + 67108864 + 25165824);
  unsigned short* qkvb  = (unsigned short*)(ws + 67108864 + 25165824 + 8388608);
  float*          bqkv  = (float*)(ws + 67108864 + 25165824 + 8388608 + 201326592);
  unsigned short* relb  = (unsigned short*)(ws + 67108864 + 25165824 + 8388608 + 201326592 + 24576);

  k_cast_f32_bf16<<<32768, 256, 0, stream>>>(x, xb, 8388608);          // 16384*2048/4
  k_build_wqkv<<<12288, 256, 0, stream>>>(wq, wk, wv, wqkvb);
  k_cast_f32_bf16<<<4096, 256, 0, stream>>>(wo, wob, 1048576);         // 2048*2048/4
  k_build_bqkv<<<24, 256, 0, stream>>>(bq, bk, bv, bqkv);
  k_build_rel<<<64, 256, 0, stream>>>(rpe, relb);

  // QKV projection: [16384][6144] = xb * wqkvb^T + bqkv  (bf16 out); grid 64x24=1536 (%8==0)
  k_gemm256<0><<<(16384 / 256) * (6144 / 256), 512, 0, stream>>>(
      xb, wqkvb, bqkv, qkvb, 16384, 6144, 2048);

  // attention -> ctx (reuses xb buffer)
  k_attn<<<16384, 256, 0, stream>>>(qkvb, relb, xb);

  // output projection: [16384][2048] = ctx * wob^T + bo  (fp32 out); grid 64x8=512 (%8==0)
  k_gemm256<1><<<(16384 / 256) * (2048 / 256), 512, 0, stream>>>(
      xb, wob, bo, (float*)d_out, 16384, 2048, 2048);
}

// Round 15
// 772.735 us; speedup vs baseline: 1.0788x; 1.0788x over previous
//
#include <hip/hip_runtime.h>
#include <hip/hip_bf16.h>
#include <stdint.h>

// B=512 L=32 E=2048 H=32 D=64 ; M = B*L = 16384 ; K = 2048 ; Nqkv = 6144
typedef __bf16 bf16x8 __attribute__((ext_vector_type(8)));
typedef float f32x4 __attribute__((ext_vector_type(4)));
typedef unsigned short u16x8 __attribute__((ext_vector_type(8)));
typedef unsigned short u16x4 __attribute__((ext_vector_type(4)));

#define G_AS __attribute__((address_space(1)))
#define L_AS __attribute__((address_space(3)))

__device__ __forceinline__ void gload_lds16(const void* g, void* l) {
  __builtin_amdgcn_global_load_lds((G_AS void*)g, (L_AS void*)l, 16, 0, 0);
}

__device__ __forceinline__ float b2f(unsigned short u) {
  union { float f; unsigned int i; } cv;
  cv.i = ((unsigned int)u) << 16;
  return cv.f;
}

__device__ __forceinline__ unsigned short f2b(float f) {
  unsigned int u = __float_as_uint(f);
  unsigned int r = u + 0x7FFFu + ((u >> 16) & 1u);  // RNE (inputs are non-NaN)
  return (unsigned short)(r >> 16);
}

// ---------------- cast / pack kernels ----------------

__global__ void k_cast_f32_bf16(const float* __restrict__ src,
                                unsigned short* __restrict__ dst, int n4) {
  int i = blockIdx.x * blockDim.x + threadIdx.x;
  if (i >= n4) return;
  float4 v = reinterpret_cast<const float4*>(src)[i];
  u16x4 o;
  o[0] = f2b(v.x); o[1] = f2b(v.y); o[2] = f2b(v.z); o[3] = f2b(v.w);
  reinterpret_cast<u16x4*>(dst)[i] = o;
}

// wqkvb rows: [0,2048)=wq, [2048,4096)=wk*0.125 (folds softmax scale), [4096,6144)=wv
__global__ void k_build_wqkv(const float* __restrict__ wq, const float* __restrict__ wk,
                             const float* __restrict__ wv, unsigned short* __restrict__ dst) {
  int i = blockIdx.x * blockDim.x + threadIdx.x;  // 6144*2048/4 = 3145728 threads
  if (i >= 3145728) return;
  int e = i << 2;
  int row = e >> 11;
  int col = e & 2047;
  const float* src; float sc = 1.0f;
  if (row < 2048) { src = wq + ((size_t)row << 11); }
  else if (row < 4096) { src = wk + ((size_t)(row - 2048) << 11); sc = 0.125f; }
  else { src = wv + ((size_t)(row - 4096) << 11); }
  float4 v = *reinterpret_cast<const float4*>(src + col);
  u16x4 o;
  o[0] = f2b(v.x * sc); o[1] = f2b(v.y * sc); o[2] = f2b(v.z * sc); o[3] = f2b(v.w * sc);
  *reinterpret_cast<u16x4*>(dst + e) = o;
}

__global__ void k_build_bqkv(const float* __restrict__ bq, const float* __restrict__ bk,
                             const float* __restrict__ bv, float* __restrict__ dst) {
  int i = blockIdx.x * blockDim.x + threadIdx.x;
  if (i >= 6144) return;
  float v;
  if (i < 2048) v = bq[i];
  else if (i < 4096) v = bk[i - 2048] * 0.125f;
  else v = bv[i - 4096];
  dst[i] = v;
}

// relb[h][j][d] = rpe[h - j + 31][d]   (faithful to the reference's H==L broadcast quirk)
__global__ void k_build_rel(const float* __restrict__ rpe, unsigned short* __restrict__ dst) {
  int i = blockIdx.x * blockDim.x + threadIdx.x;  // 32*32*16 = 16384
  if (i >= 16384) return;
  int h = i >> 9;
  int j = (i >> 4) & 31;
  int d = (i & 15) << 2;
  const float* s = rpe + (size_t)(h - j + 31) * 64 + d;
  float4 v = *reinterpret_cast<const float4*>(s);
  u16x4 o;
  o[0] = f2b(v.x); o[1] = f2b(v.y); o[2] = f2b(v.z); o[3] = f2b(v.w);
  *reinterpret_cast<u16x4*>(dst + ((size_t)i << 2)) = o;
}

// ---------------- GEMM: C[M][N] = A[M][K] * B[N][K]^T + bias[N] ----------------
// Round-8 structure (best measured: 472 us QKV, 873 TF): 256x256 tile, 8 waves
// (2Mx4N), 512 threads, BK=32, 3-buffer LDS ring (96 KiB), counted vmcnt(4) once
// per tile, setprio around MFMA, bm-major bijective XCD swizzle, XOR-swizzled LDS
// (0 conflicts + 64B-line staging coalescing).
//
// TWOBAR=0: exact round-8 (4 barriers/tile) — used for out-proj (baseline anchor).
// TWOBAR=1: the two non-load-bearing barriers removed (2 barriers/tile):
//   { reads bf+afL; stage A(t+2); 16 MFMA; reads afH; stage B(t+2); vmcnt(4);
//     BAR1; 16 MFMA; BAR2 }
//  Load-bearing analysis: BAR1 (after vmcnt) = block-wide landing of tile t+1
//  (frag reads cross wave staging ownership -> must be block-wide). BAR2 = WAR
//  drain: all buf-t reads are lgkm-consumed by this tile's MFMAs before BAR2,
//  and iter t+1's stage into slot (t-1)%3... (t+1)+2 = t+3 = t%3's successor —
//  slot (t+3)%3 = (t)%3 — wait: ring of 3, stage at iter u targets (u+2)%3 whose
//  readers were iter u-1, drained at iter u-1's BAR2. Stage issues after that
//  BAR2 in program order. ph0's pre/post-MFMA barriers protected nothing
//  (per-wave lgkm-waited frag reads from an already-valid buffer).

template <int OUT_F32, int TWOBAR>
__global__ __launch_bounds__(512, 1)
void k_gemm256(const unsigned short* __restrict__ A,
               const unsigned short* __restrict__ B,
               const float* __restrict__ bias,
               void* __restrict__ Cptr,
               int M, int N, int K)
{
  __shared__ __align__(16) unsigned short As[3][8192];
  __shared__ __align__(16) unsigned short Bs[3][8192];

  // bijective XCD swizzle, bm-major
  const int nbn = N >> 8;
  const int cpx = gridDim.x >> 3;
  const int orig = blockIdx.x;
  const int wg = (orig & 7) * cpx + (orig >> 3);
  const int bm = wg / nbn;
  const int bn = wg % nbn;

  const int tid = threadIdx.x;
  const int lane = tid & 63;
  const int wid = tid >> 6;
  const int wr = wid >> 2;   // 0..1  (m-half)
  const int wc = wid & 3;    // 0..3  (64-col strip)

  // staging: chunk c=tid -> row tid>>2 (0..127), chunk c+512 -> row+128.
  const int rs = tid >> 2;
  const int cs = ((tid & 3) ^ ((tid >> 3) & 3)) << 3;
  const unsigned short* agA0 = A + (size_t)(bm * 256 + rs) * K + cs;
  const unsigned short* agA1 = agA0 + (size_t)128 * K;
  const unsigned short* agB0 = B + (size_t)(bn * 256 + rs) * K + cs;
  const unsigned short* agB1 = agB0 + (size_t)128 * K;
  const int ldst = tid * 8;

  // fragment read offsets (ushort index inside one 8192-ushort matrix-buf)
  const int fr = lane & 15;
  const int q  = lane >> 4;                       // k-slot 0..3
  const int sx = q ^ ((fr >> 1) & 3);             // swizzled slot (lane constant)
  const int rbase = fr * 32 + sx * 8;
  const int aOff = wr * 4096 + rbase;             // + m*512, m=0..7
  const int bOff = wc * 2048 + rbase;             // + n*512, n=0..3

  f32x4 acc[8][4] = {};
  const int NT = K >> 5;   // 64 K-tiles

  // prologue: stage tiles 0,1 into bufs 0,1
#pragma unroll
  for (int pf = 0; pf < 2; ++pf) {
    const int kof = pf << 5;
    gload_lds16(agA0 + kof, &As[pf][ldst]);
    gload_lds16(agA1 + kof, &As[pf][ldst + 4096]);
    gload_lds16(agB0 + kof, &Bs[pf][ldst]);
    gload_lds16(agB1 + kof, &Bs[pf][ldst + 4096]);
  }
  asm volatile("s_waitcnt vmcnt(4)" ::: "memory");   // tile 0 landed
  asm volatile("s_barrier" ::: "memory");

  int rb = 0;   // buf of tile t
  int sb = 2;   // buf of tile t+2
  for (int t = 0; t < NT; ++t) {
    const unsigned short* ab = &As[rb][0];
    const unsigned short* bb = &Bs[rb][0];
    const bool st = (t + 2) < NT;               // uniform
    const int kof = (t + 2) << 5;

    // ===== phase 0: A-low + B frags, stage A(t+2) =====
    bf16x8 afL[4], bf[4];
#pragma unroll
    for (int n = 0; n < 4; ++n)
      bf[n] = *reinterpret_cast<const bf16x8*>(bb + bOff + n * 512);
#pragma unroll
    for (int m = 0; m < 4; ++m)
      afL[m] = *reinterpret_cast<const bf16x8*>(ab + aOff + m * 512);
    if (st) {
      gload_lds16(agA0 + kof, &As[sb][ldst]);
      gload_lds16(agA1 + kof, &As[sb][ldst + 4096]);
    }
    if (!TWOBAR) {
      __builtin_amdgcn_sched_barrier(0);
      asm volatile("s_barrier" ::: "memory");
      __builtin_amdgcn_sched_barrier(0);
    }
    __builtin_amdgcn_s_setprio(1);
#pragma unroll
    for (int m = 0; m < 4; ++m)
#pragma unroll
      for (int n = 0; n < 4; ++n)
        acc[m][n] = __builtin_amdgcn_mfma_f32_16x16x32_bf16(afL[m], bf[n], acc[m][n], 0, 0, 0);
    __builtin_amdgcn_s_setprio(0);
    if (!TWOBAR) {
      __builtin_amdgcn_sched_barrier(0);
      asm volatile("s_barrier" ::: "memory");
    }

    // ===== phase 1: A-high frags, stage B(t+2), counted wait =====
    bf16x8 afH[4];
#pragma unroll
    for (int m = 0; m < 4; ++m)
      afH[m] = *reinterpret_cast<const bf16x8*>(ab + aOff + (4 + m) * 512);
    if (st) {
      gload_lds16(agB0 + kof, &Bs[sb][ldst]);
      gload_lds16(agB1 + kof, &Bs[sb][ldst + 4096]);
    }
    if (t < NT - 2)       asm volatile("s_waitcnt vmcnt(4)" ::: "memory");
    else if (t == NT - 2) asm volatile("s_waitcnt vmcnt(0)" ::: "memory");
    __builtin_amdgcn_sched_barrier(0);
    asm volatile("s_barrier" ::: "memory");     // BAR1: tile t+1 landed block-wide
    __builtin_amdgcn_sched_barrier(0);
    __builtin_amdgcn_s_setprio(1);
#pragma unroll
    for (int m = 0; m < 4; ++m)
#pragma unroll
      for (int n = 0; n < 4; ++n)
        acc[4 + m][n] = __builtin_amdgcn_mfma_f32_16x16x32_bf16(afH[m], bf[n], acc[4 + m][n], 0, 0, 0);
    __builtin_amdgcn_s_setprio(0);
    __builtin_amdgcn_sched_barrier(0);
    asm volatile("s_barrier" ::: "memory");     // BAR2: buf-t reads drained (WAR)

    rb = (rb == 2) ? 0 : rb + 1;
    sb = (sb == 2) ? 0 : sb + 1;
  }

  // epilogue: C/D layout col = lane&15, row = (lane>>4)*4 + reg
  const int rBase = bm * 256 + wr * 128 + (q << 2);
  const int cBase = bn * 256 + wc * 64 + fr;
#pragma unroll
  for (int n = 0; n < 4; ++n) {
    const int col = cBase + n * 16;
    const float bv = bias[col];
#pragma unroll
    for (int m = 0; m < 8; ++m) {
      const int row = rBase + m * 16;
#pragma unroll
      for (int r = 0; r < 4; ++r) {
        float v = acc[m][n][r] + bv;
        if (OUT_F32) {
          reinterpret_cast<float*>(Cptr)[(size_t)(row + r) * N + col] = v;
        } else {
          reinterpret_cast<unsigned short*>(Cptr)[(size_t)(row + r) * N + col] = f2b(v);
        }
      }
    }
  }
}

// ---------------- attention: one block (256 thr) per (b,h) ----------------
// shfl-softmax (round-14 win) with the ALIGNMENT FIX: stride back to 68 floats
// (68 % 4 == 0 -> every float4 LDS access is 16B-aligned; stride 66 made odd
// rows 8B-aligned -> misaligned b128 split, the round-14 regression).
// 1/den folded into P before the broadcast write.

__global__ __launch_bounds__(256)
void k_attn(const unsigned short* __restrict__ qkv,
            const unsigned short* __restrict__ relb,
            unsigned short* __restrict__ ctx)
{
  __shared__ float qL[32][68];
  __shared__ float krL[32][68];
  __shared__ float vL[32][68];
  __shared__ float PL[32][33];

  const int bh = blockIdx.x;
  const int b = bh >> 5;
  const int h = bh & 31;
  const int t = threadIdx.x;
  const int r = t >> 3;           // row 0..31
  const int d0 = (t & 7) << 3;    // d 0..56 step 8

  const unsigned short* base = qkv + (size_t)(b * 32 + r) * 6144 + h * 64 + d0;
  u16x8 uq = *reinterpret_cast<const u16x8*>(base);
  u16x8 uk = *reinterpret_cast<const u16x8*>(base + 2048);
  u16x8 uv = *reinterpret_cast<const u16x8*>(base + 4096);
  u16x8 ur = *reinterpret_cast<const u16x8*>(relb + (((size_t)(h * 32 + r)) << 6) + d0);

  float fq[8], fkr[8], fv[8];
#pragma unroll
  for (int c = 0; c < 8; ++c) {
    fq[c] = b2f(uq[c]);
    fkr[c] = b2f(uk[c]) + b2f(ur[c]);
    fv[c] = b2f(uv[c]);
  }
  *reinterpret_cast<float4*>(&qL[r][d0])      = make_float4(fq[0], fq[1], fq[2], fq[3]);
  *reinterpret_cast<float4*>(&qL[r][d0 + 4])  = make_float4(fq[4], fq[5], fq[6], fq[7]);
  *reinterpret_cast<float4*>(&krL[r][d0])     = make_float4(fkr[0], fkr[1], fkr[2], fkr[3]);
  *reinterpret_cast<float4*>(&krL[r][d0 + 4]) = make_float4(fkr[4], fkr[5], fkr[6], fkr[7]);
  *reinterpret_cast<float4*>(&vL[r][d0])      = make_float4(fv[0], fv[1], fv[2], fv[3]);
  *reinterpret_cast<float4*>(&vL[r][d0 + 4])  = make_float4(fv[4], fv[5], fv[6], fv[7]);
  __syncthreads();

  const int i = r;
  const int j0 = (t & 7) << 2;   // 4 score cols per thread
  float s0 = 0.f, s1 = 0.f, s2 = 0.f, s3 = 0.f;
#pragma unroll
  for (int d = 0; d < 64; d += 4) {
    float4 qv = *reinterpret_cast<const float4*>(&qL[i][d]);
    float4 k0 = *reinterpret_cast<const float4*>(&krL[j0 + 0][d]);
    float4 k1 = *reinterpret_cast<const float4*>(&krL[j0 + 1][d]);
    float4 k2 = *reinterpret_cast<const float4*>(&krL[j0 + 2][d]);
    float4 k3 = *reinterpret_cast<const float4*>(&krL[j0 + 3][d]);
    s0 += qv.x * k0.x + qv.y * k0.y + qv.z * k0.z + qv.w * k0.w;
    s1 += qv.x * k1.x + qv.y * k1.y + qv.z * k1.z + qv.w * k1.w;
    s2 += qv.x * k2.x + qv.y * k2.y + qv.z * k2.z + qv.w * k2.w;
    s3 += qv.x * k3.x + qv.y * k3.y + qv.z * k3.z + qv.w * k3.w;
  }

  // in-register softmax over the row (8 threads x 4 values; the 8-thread row
  // group is 8 consecutive lanes -> never crosses a wave)
  float mx = fmaxf(fmaxf(s0, s1), fmaxf(s2, s3));
  mx = fmaxf(mx, __shfl_xor(mx, 1));
  mx = fmaxf(mx, __shfl_xor(mx, 2));
  mx = fmaxf(mx, __shfl_xor(mx, 4));
  float p0 = __expf(s0 - mx), p1 = __expf(s1 - mx), p2 = __expf(s2 - mx), p3 = __expf(s3 - mx);
  float sm = p0 + p1 + p2 + p3;
  sm += __shfl_xor(sm, 1);
  sm += __shfl_xor(sm, 2);
  sm += __shfl_xor(sm, 4);
  const float inv = 1.0f / sm;
  PL[i][j0 + 0] = p0 * inv; PL[i][j0 + 1] = p1 * inv;
  PL[i][j0 + 2] = p2 * inv; PL[i][j0 + 3] = p3 * inv;
  __syncthreads();

  float o[8] = {0.f, 0.f, 0.f, 0.f, 0.f, 0.f, 0.f, 0.f};
#pragma unroll
  for (int jj = 0; jj < 32; ++jj) {
    float pj = PL[i][jj];
    float4 v0 = *reinterpret_cast<const float4*>(&vL[jj][d0]);
    float4 v1 = *reinterpret_cast<const float4*>(&vL[jj][d0 + 4]);
    o[0] += pj * v0.x; o[1] += pj * v0.y; o[2] += pj * v0.z; o[3] += pj * v0.w;
    o[4] += pj * v1.x; o[5] += pj * v1.y; o[6] += pj * v1.z; o[7] += pj * v1.w;
  }
  u16x8 ov;
#pragma unroll
  for (int c = 0; c < 8; ++c) ov[c] = f2b(o[c]);
  *reinterpret_cast<u16x8*>(ctx + (size_t)(b * 32 + i) * 2048 + h * 64 + d0) = ov;
}

// ---------------- launch ----------------

extern "C" void kernel_launch(void* const* d_in, const int* in_sizes, int n_in,
                              void* d_out, int out_size, void* d_ws, size_t ws_size,
                              hipStream_t stream) {
  const float* x   = (const float*)d_in[0];
  const float* wq  = (const float*)d_in[1];
  const float* bq  = (const float*)d_in[2];
  const float* wk  = (const float*)d_in[3];
  const float* bk  = (const float*)d_in[4];
  const float* wv  = (const float*)d_in[5];
  const float* bv  = (const float*)d_in[6];
  const float* wo  = (const float*)d_in[7];
  const float* bo  = (const float*)d_in[8];
  const float* rpe = (const float*)d_in[9];

  char* ws = (char*)d_ws;
  unsigned short* xb    = (unsigned short*)(ws);
  unsigned short* wqkvb = (unsigned short*)(ws + 67108864);
  unsigned short* wob   = (unsigned short*)(ws + 67108864 + 25165824);
  unsigned short* qkvb  = (unsigned short*)(ws + 67108864 + 25165824 + 8388608);
  float*          bqkv  = (float*)(ws + 67108864 + 25165824 + 8388608 + 201326592);
  unsigned short* relb  = (unsigned short*)(ws + 67108864 + 25165824 + 8388608 + 201326592 + 24576);

  k_cast_f32_bf16<<<32768, 256, 0, stream>>>(x, xb, 8388608);          // 16384*2048/4
  k_build_wqkv<<<12288, 256, 0, stream>>>(wq, wk, wv, wqkvb);
  k_cast_f32_bf16<<<4096, 256, 0, stream>>>(wo, wob, 1048576);         // 2048*2048/4
  k_build_bqkv<<<24, 256, 0, stream>>>(bq, bk, bv, bqkv);
  k_build_rel<<<64, 256, 0, stream>>>(rpe, relb);

  // QKV projection (TWOBAR=1 experiment): grid 64x24=1536 (%8==0)
  k_gemm256<0, 1><<<(16384 / 256) * (6144 / 256), 512, 0, stream>>>(
      xb, wqkvb, bqkv, qkvb, 16384, 6144, 2048);

  // attention -> ctx (reuses xb buffer)
  k_attn<<<16384, 256, 0, stream>>>(qkvb, relb, xb);

  // output projection (round-8 exact, baseline anchor): grid 64x8=512 (%8==0)
  k_gemm256<1, 0><<<(16384 / 256) * (2048 / 256), 512, 0, stream>>>(
      xb, wob, bo, (float*)d_out, 16384, 2048, 2048);
}

// Round 16
// 710.740 us; speedup vs baseline: 1.1729x; 1.0872x over previous
//
#include <hip/hip_runtime.h>
#include <hip/hip_bf16.h>
#include <stdint.h>

// B=512 L=32 E=2048 H=32 D=64 ; M = B*L = 16384 ; K = 2048 ; Nqkv = 6144
typedef __bf16 bf16x8 __attribute__((ext_vector_type(8)));
typedef float f32x4 __attribute__((ext_vector_type(4)));
typedef unsigned short u16x8 __attribute__((ext_vector_type(8)));
typedef unsigned short u16x4 __attribute__((ext_vector_type(4)));

#define G_AS __attribute__((address_space(1)))
#define L_AS __attribute__((address_space(3)))

__device__ __forceinline__ void gload_lds16(const void* g, void* l) {
  __builtin_amdgcn_global_load_lds((G_AS void*)g, (L_AS void*)l, 16, 0, 0);
}

__device__ __forceinline__ float b2f(unsigned short u) {
  union { float f; unsigned int i; } cv;
  cv.i = ((unsigned int)u) << 16;
  return cv.f;
}

__device__ __forceinline__ unsigned short f2b(float f) {
  unsigned int u = __float_as_uint(f);
  unsigned int r = u + 0x7FFFu + ((u >> 16) & 1u);  // RNE (inputs are non-NaN)
  return (unsigned short)(r >> 16);
}

// ---------------- cast / pack kernels ----------------

__global__ void k_cast_f32_bf16(const float* __restrict__ src,
                                unsigned short* __restrict__ dst, int n4) {
  int i = blockIdx.x * blockDim.x + threadIdx.x;
  if (i >= n4) return;
  float4 v = reinterpret_cast<const float4*>(src)[i];
  u16x4 o;
  o[0] = f2b(v.x); o[1] = f2b(v.y); o[2] = f2b(v.z); o[3] = f2b(v.w);
  reinterpret_cast<u16x4*>(dst)[i] = o;
}

// wqkvb rows: [0,2048)=wq, [2048,4096)=wk*0.125 (folds softmax scale), [4096,6144)=wv
__global__ void k_build_wqkv(const float* __restrict__ wq, const float* __restrict__ wk,
                             const float* __restrict__ wv, unsigned short* __restrict__ dst) {
  int i = blockIdx.x * blockDim.x + threadIdx.x;  // 6144*2048/4 = 3145728 threads
  if (i >= 3145728) return;
  int e = i << 2;
  int row = e >> 11;
  int col = e & 2047;
  const float* src; float sc = 1.0f;
  if (row < 2048) { src = wq + ((size_t)row << 11); }
  else if (row < 4096) { src = wk + ((size_t)(row - 2048) << 11); sc = 0.125f; }
  else { src = wv + ((size_t)(row - 4096) << 11); }
  float4 v = *reinterpret_cast<const float4*>(src + col);
  u16x4 o;
  o[0] = f2b(v.x * sc); o[1] = f2b(v.y * sc); o[2] = f2b(v.z * sc); o[3] = f2b(v.w * sc);
  *reinterpret_cast<u16x4*>(dst + e) = o;
}

__global__ void k_build_bqkv(const float* __restrict__ bq, const float* __restrict__ bk,
                             const float* __restrict__ bv, float* __restrict__ dst) {
  int i = blockIdx.x * blockDim.x + threadIdx.x;
  if (i >= 6144) return;
  float v;
  if (i < 2048) v = bq[i];
  else if (i < 4096) v = bk[i - 2048] * 0.125f;
  else v = bv[i - 4096];
  dst[i] = v;
}

// relb[h][j][d] = rpe[h - j + 31][d]   (faithful to the reference's H==L broadcast quirk)
__global__ void k_build_rel(const float* __restrict__ rpe, unsigned short* __restrict__ dst) {
  int i = blockIdx.x * blockDim.x + threadIdx.x;  // 32*32*16 = 16384
  if (i >= 16384) return;
  int h = i >> 9;
  int j = (i >> 4) & 31;
  int d = (i & 15) << 2;
  const float* s = rpe + (size_t)(h - j + 31) * 64 + d;
  float4 v = *reinterpret_cast<const float4*>(s);
  u16x4 o;
  o[0] = f2b(v.x); o[1] = f2b(v.y); o[2] = f2b(v.z); o[3] = f2b(v.w);
  *reinterpret_cast<u16x4*>(dst + ((size_t)i << 2)) = o;
}

// ---------------- GEMM: C[M][N] = A[M][K] * B[N][K]^T + bias[N] ----------------
// Round-15 winner: 256x256 tile, 8 waves (2Mx4N), 512 threads, BK=32, 3-buffer
// LDS ring (96 KiB), 2 barriers/K-tile, counted vmcnt(4), setprio, bm-major XCD
// swizzle, XOR-swizzled LDS (0 conflicts + 64B-line staging coalescing).
// Per K-tile: { reads bf+afL; stage A(t+2); 16 MFMA; reads afH; stage B(t+2);
//               vmcnt(4); BAR1; 16 MFMA; BAR2 }
// BAR1 = block-wide landing of tile t+1; BAR2 = WAR drain for slot re-stage.

template <int OUT_F32>
__global__ __launch_bounds__(512, 1)
void k_gemm256(const unsigned short* __restrict__ A,
               const unsigned short* __restrict__ B,
               const float* __restrict__ bias,
               void* __restrict__ Cptr,
               int M, int N, int K)
{
  __shared__ __align__(16) unsigned short As[3][8192];
  __shared__ __align__(16) unsigned short Bs[3][8192];

  const int nbn = N >> 8;
  const int cpx = gridDim.x >> 3;
  const int orig = blockIdx.x;
  const int wg = (orig & 7) * cpx + (orig >> 3);
  const int bm = wg / nbn;
  const int bn = wg % nbn;

  const int tid = threadIdx.x;
  const int lane = tid & 63;
  const int wid = tid >> 6;
  const int wr = wid >> 2;
  const int wc = wid & 3;

  const int rs = tid >> 2;
  const int cs = ((tid & 3) ^ ((tid >> 3) & 3)) << 3;
  const unsigned short* agA0 = A + (size_t)(bm * 256 + rs) * K + cs;
  const unsigned short* agA1 = agA0 + (size_t)128 * K;
  const unsigned short* agB0 = B + (size_t)(bn * 256 + rs) * K + cs;
  const unsigned short* agB1 = agB0 + (size_t)128 * K;
  const int ldst = tid * 8;

  const int fr = lane & 15;
  const int q  = lane >> 4;
  const int sx = q ^ ((fr >> 1) & 3);
  const int rbase = fr * 32 + sx * 8;
  const int aOff = wr * 4096 + rbase;
  const int bOff = wc * 2048 + rbase;

  f32x4 acc[8][4] = {};
  const int NT = K >> 5;

#pragma unroll
  for (int pf = 0; pf < 2; ++pf) {
    const int kof = pf << 5;
    gload_lds16(agA0 + kof, &As[pf][ldst]);
    gload_lds16(agA1 + kof, &As[pf][ldst + 4096]);
    gload_lds16(agB0 + kof, &Bs[pf][ldst]);
    gload_lds16(agB1 + kof, &Bs[pf][ldst + 4096]);
  }
  asm volatile("s_waitcnt vmcnt(4)" ::: "memory");
  asm volatile("s_barrier" ::: "memory");

  int rb = 0;
  int sb = 2;
  for (int t = 0; t < NT; ++t) {
    const unsigned short* ab = &As[rb][0];
    const unsigned short* bb = &Bs[rb][0];
    const bool st = (t + 2) < NT;
    const int kof = (t + 2) << 5;

    bf16x8 afL[4], bf[4];
#pragma unroll
    for (int n = 0; n < 4; ++n)
      bf[n] = *reinterpret_cast<const bf16x8*>(bb + bOff + n * 512);
#pragma unroll
    for (int m = 0; m < 4; ++m)
      afL[m] = *reinterpret_cast<const bf16x8*>(ab + aOff + m * 512);
    if (st) {
      gload_lds16(agA0 + kof, &As[sb][ldst]);
      gload_lds16(agA1 + kof, &As[sb][ldst + 4096]);
    }
    __builtin_amdgcn_s_setprio(1);
#pragma unroll
    for (int m = 0; m < 4; ++m)
#pragma unroll
      for (int n = 0; n < 4; ++n)
        acc[m][n] = __builtin_amdgcn_mfma_f32_16x16x32_bf16(afL[m], bf[n], acc[m][n], 0, 0, 0);
    __builtin_amdgcn_s_setprio(0);

    bf16x8 afH[4];
#pragma unroll
    for (int m = 0; m < 4; ++m)
      afH[m] = *reinterpret_cast<const bf16x8*>(ab + aOff + (4 + m) * 512);
    if (st) {
      gload_lds16(agB0 + kof, &Bs[sb][ldst]);
      gload_lds16(agB1 + kof, &Bs[sb][ldst + 4096]);
    }
    if (t < NT - 2)       asm volatile("s_waitcnt vmcnt(4)" ::: "memory");
    else if (t == NT - 2) asm volatile("s_waitcnt vmcnt(0)" ::: "memory");
    __builtin_amdgcn_sched_barrier(0);
    asm volatile("s_barrier" ::: "memory");     // BAR1
    __builtin_amdgcn_sched_barrier(0);
    __builtin_amdgcn_s_setprio(1);
#pragma unroll
    for (int m = 0; m < 4; ++m)
#pragma unroll
      for (int n = 0; n < 4; ++n)
        acc[4 + m][n] = __builtin_amdgcn_mfma_f32_16x16x32_bf16(afH[m], bf[n], acc[4 + m][n], 0, 0, 0);
    __builtin_amdgcn_s_setprio(0);
    __builtin_amdgcn_sched_barrier(0);
    asm volatile("s_barrier" ::: "memory");     // BAR2

    rb = (rb == 2) ? 0 : rb + 1;
    sb = (sb == 2) ? 0 : sb + 1;
  }

  const int rBase = bm * 256 + wr * 128 + (q << 2);
  const int cBase = bn * 256 + wc * 64 + fr;
#pragma unroll
  for (int n = 0; n < 4; ++n) {
    const int col = cBase + n * 16;
    const float bv = bias[col];
#pragma unroll
    for (int m = 0; m < 8; ++m) {
      const int row = rBase + m * 16;
#pragma unroll
      for (int r = 0; r < 4; ++r) {
        float v = acc[m][n][r] + bv;
        if (OUT_F32) {
          reinterpret_cast<float*>(Cptr)[(size_t)(row + r) * N + col] = v;
        } else {
          reinterpret_cast<unsigned short*>(Cptr)[(size_t)(row + r) * N + col] = f2b(v);
        }
      }
    }
  }
}

// ---------------- MFMA attention: one WAVE per (b,h), 4 waves/block ----------------
// Per wave: Q[32,64], KR[32,64] (k_scaled + rel, bf16), V^T[64,32] staged in a
// private LDS region (no cross-wave sharing -> ZERO barriers; lgkmcnt fences at
// the two write->read handoffs).
//  QK^T: S[32,32] = Q·KR^T  -- A·B^T frag pattern identical to the GEMM (proven):
//    a-frag: row = 16m + (lane&15), k = 32ks + (lane>>4)*8  (b128)
//    b-frag: row = 16n + (lane&15) of KR, same k            (b128)
//    S frag (m,n): i = 16m + (lane>>4)*4 + r, j = 16n + (lane&15)
//  Softmax: row i lives in 16 lanes x 2 n-frags -> fmax/add + shfl_xor(1,2,4,8).
//  P (normalized, bf16) -> pS[32][40]; PV: ctx = P·V = A·(V^T)^T, K=32, 1 MFMA/frag.
// LDS strides: qS/krS 72 ushorts (144B, 16B-aligned rows); vTS/pS 40 ushorts (80B).

__global__ __launch_bounds__(256)
void k_attn(const unsigned short* __restrict__ qkv,
            const unsigned short* __restrict__ relb,
            unsigned short* __restrict__ ctx)
{
  __shared__ __align__(16) unsigned short qS[4][32 * 72];
  __shared__ __align__(16) unsigned short krS[4][32 * 72];
  __shared__ __align__(16) unsigned short vTS[4][64 * 40];
  __shared__ __align__(16) unsigned short pS[4][32 * 40];

  const int w = threadIdx.x >> 6;
  const int lane = threadIdx.x & 63;
  const int b = blockIdx.x >> 3;
  const int h = ((blockIdx.x & 7) << 2) + w;

  // ---- staging: lane covers row r = lane>>1, d-range d0 = (lane&1)*32 ----
  const int r = lane >> 1;
  const int d0 = (lane & 1) << 5;
  const unsigned short* base = qkv + (size_t)(b * 32 + r) * 6144 + h * 64 + d0;
  const unsigned short* relp = relb + (((size_t)(h * 32 + r)) << 6) + d0;

  u16x8 uq[4], uk[4], uv[4], ur[4];
#pragma unroll
  for (int c = 0; c < 4; ++c) {
    uq[c] = *reinterpret_cast<const u16x8*>(base + 8 * c);
    uk[c] = *reinterpret_cast<const u16x8*>(base + 2048 + 8 * c);
    uv[c] = *reinterpret_cast<const u16x8*>(base + 4096 + 8 * c);
    ur[c] = *reinterpret_cast<const u16x8*>(relp + 8 * c);
  }
  // q: raw copy ; kr = k_s + rel (fp32 add, bf16 round) ; v: transposed scalar copy
#pragma unroll
  for (int c = 0; c < 4; ++c) {
    *reinterpret_cast<u16x8*>(&qS[w][r * 72 + d0 + 8 * c]) = uq[c];
    u16x8 kr;
#pragma unroll
    for (int e = 0; e < 8; ++e) kr[e] = f2b(b2f(uk[c][e]) + b2f(ur[c][e]));
    *reinterpret_cast<u16x8*>(&krS[w][r * 72 + d0 + 8 * c]) = kr;
#pragma unroll
    for (int e = 0; e < 8; ++e) vTS[w][(d0 + 8 * c + e) * 40 + r] = uv[c][e];
  }
  asm volatile("s_waitcnt lgkmcnt(0)" ::: "memory");
  __builtin_amdgcn_sched_barrier(0);

  // ---- QK^T: 8 MFMA ----
  const int fr16 = lane & 15;
  const int qq = lane >> 4;
  f32x4 accs[2][2] = {};
#pragma unroll
  for (int ks = 0; ks < 2; ++ks) {
    bf16x8 aq[2], bk[2];
#pragma unroll
    for (int m = 0; m < 2; ++m)
      aq[m] = *reinterpret_cast<const bf16x8*>(&qS[w][(16 * m + fr16) * 72 + 32 * ks + qq * 8]);
#pragma unroll
    for (int n = 0; n < 2; ++n)
      bk[n] = *reinterpret_cast<const bf16x8*>(&krS[w][(16 * n + fr16) * 72 + 32 * ks + qq * 8]);
#pragma unroll
    for (int m = 0; m < 2; ++m)
#pragma unroll
      for (int n = 0; n < 2; ++n)
        accs[m][n] = __builtin_amdgcn_mfma_f32_16x16x32_bf16(aq[m], bk[n], accs[m][n], 0, 0, 0);
  }

  // ---- in-register softmax per row i = 16m + qq*4 + rr ----
#pragma unroll
  for (int m = 0; m < 2; ++m) {
#pragma unroll
    for (int rr = 0; rr < 4; ++rr) {
      float a0 = accs[m][0][rr], a1 = accs[m][1][rr];
      float mx = fmaxf(a0, a1);
      mx = fmaxf(mx, __shfl_xor(mx, 1));
      mx = fmaxf(mx, __shfl_xor(mx, 2));
      mx = fmaxf(mx, __shfl_xor(mx, 4));
      mx = fmaxf(mx, __shfl_xor(mx, 8));
      float p0 = __expf(a0 - mx), p1 = __expf(a1 - mx);
      float sm = p0 + p1;
      sm += __shfl_xor(sm, 1);
      sm += __shfl_xor(sm, 2);
      sm += __shfl_xor(sm, 4);
      sm += __shfl_xor(sm, 8);
      const float inv = 1.0f / sm;
      const int i = 16 * m + qq * 4 + rr;
      pS[w][i * 40 + fr16]      = f2b(p0 * inv);
      pS[w][i * 40 + 16 + fr16] = f2b(p1 * inv);
    }
  }
  asm volatile("s_waitcnt lgkmcnt(0)" ::: "memory");
  __builtin_amdgcn_sched_barrier(0);

  // ---- PV: ctx[32,64] = P[32,32] · V[32,64] = A·(V^T)^T, K=32, 8 MFMA ----
  bf16x8 ap[2], bv[4];
#pragma unroll
  for (int m = 0; m < 2; ++m)
    ap[m] = *reinterpret_cast<const bf16x8*>(&pS[w][(16 * m + fr16) * 40 + qq * 8]);
#pragma unroll
  for (int n = 0; n < 4; ++n)
    bv[n] = *reinterpret_cast<const bf16x8*>(&vTS[w][(16 * n + fr16) * 40 + qq * 8]);
  f32x4 acco[2][4] = {};
#pragma unroll
  for (int m = 0; m < 2; ++m)
#pragma unroll
    for (int n = 0; n < 4; ++n)
      acco[m][n] = __builtin_amdgcn_mfma_f32_16x16x32_bf16(ap[m], bv[n], acco[m][n], 0, 0, 0);

  // ---- store ctx (C/D layout: col = lane&15, row = qq*4 + reg) ----
#pragma unroll
  for (int m = 0; m < 2; ++m) {
#pragma unroll
    for (int rr = 0; rr < 4; ++rr) {
      const int i = 16 * m + qq * 4 + rr;
      unsigned short* orow = ctx + (size_t)(b * 32 + i) * 2048 + h * 64;
#pragma unroll
      for (int n = 0; n < 4; ++n)
        orow[16 * n + fr16] = f2b(acco[m][n][rr]);
    }
  }
}

// ---------------- launch ----------------

extern "C" void kernel_launch(void* const* d_in, const int* in_sizes, int n_in,
                              void* d_out, int out_size, void* d_ws, size_t ws_size,
                              hipStream_t stream) {
  const float* x   = (const float*)d_in[0];
  const float* wq  = (const float*)d_in[1];
  const float* bq  = (const float*)d_in[2];
  const float* wk  = (const float*)d_in[3];
  const float* bk  = (const float*)d_in[4];
  const float* wv  = (const float*)d_in[5];
  const float* bv  = (const float*)d_in[6];
  const float* wo  = (const float*)d_in[7];
  const float* bo  = (const float*)d_in[8];
  const float* rpe = (const float*)d_in[9];

  char* ws = (char*)d_ws;
  unsigned short* xb    = (unsigned short*)(ws);
  unsigned short* wqkvb = (unsigned short*)(ws + 67108864);
  unsigned short* wob   = (unsigned short*)(ws + 67108864 + 25165824);
  unsigned short* qkvb  = (unsigned short*)(ws + 67108864 + 25165824 + 8388608);
  float*          bqkv  = (float*)(ws + 67108864 + 25165824 + 8388608 + 201326592);
  unsigned short* relb  = (unsigned short*)(ws + 67108864 + 25165824 + 8388608 + 201326592 + 24576);

  k_cast_f32_bf16<<<32768, 256, 0, stream>>>(x, xb, 8388608);          // 16384*2048/4
  k_build_wqkv<<<12288, 256, 0, stream>>>(wq, wk, wv, wqkvb);
  k_cast_f32_bf16<<<4096, 256, 0, stream>>>(wo, wob, 1048576);         // 2048*2048/4
  k_build_bqkv<<<24, 256, 0, stream>>>(bq, bk, bv, bqkv);
  k_build_rel<<<64, 256, 0, stream>>>(rpe, relb);

  // QKV projection: grid 64x24=1536 (%8==0)
  k_gemm256<0><<<(16384 / 256) * (6144 / 256), 512, 0, stream>>>(
      xb, wqkvb, bqkv, qkvb, 16384, 6144, 2048);

  // MFMA attention -> ctx (reuses xb buffer); 4096 blocks, wave per (b,h)
  k_attn<<<4096, 256, 0, stream>>>(qkvb, relb, xb);

  // output projection: grid 64x8=512 (%8==0)
  k_gemm256<1><<<(16384 / 256) * (2048 / 256), 512, 0, stream>>>(
      xb, wob, bo, (float*)d_out, 16384, 2048, 2048);
}

// Round 17
// 704.610 us; speedup vs baseline: 1.1831x; 1.0087x over previous
//
#include <hip/hip_runtime.h>
#include <hip/hip_bf16.h>
#include <stdint.h>

// B=512 L=32 E=2048 H=32 D=64 ; M = B*L = 16384 ; K = 2048 ; Nqkv = 6144
typedef __bf16 bf16x8 __attribute__((ext_vector_type(8)));
typedef float f32x4 __attribute__((ext_vector_type(4)));
typedef unsigned short u16x8 __attribute__((ext_vector_type(8)));
typedef unsigned short u16x4 __attribute__((ext_vector_type(4)));

#define G_AS __attribute__((address_space(1)))
#define L_AS __attribute__((address_space(3)))

__device__ __forceinline__ void gload_lds16(const void* g, void* l) {
  __builtin_amdgcn_global_load_lds((G_AS void*)g, (L_AS void*)l, 16, 0, 0);
}

__device__ __forceinline__ float b2f(unsigned short u) {
  union { float f; unsigned int i; } cv;
  cv.i = ((unsigned int)u) << 16;
  return cv.f;
}

__device__ __forceinline__ unsigned short f2b(float f) {
  unsigned int u = __float_as_uint(f);
  unsigned int r = u + 0x7FFFu + ((u >> 16) & 1u);  // RNE (inputs are non-NaN)
  return (unsigned short)(r >> 16);
}

// ---------------- cast / pack kernels ----------------

__global__ void k_cast_f32_bf16(const float* __restrict__ src,
                                unsigned short* __restrict__ dst, int n4) {
  int i = blockIdx.x * blockDim.x + threadIdx.x;
  if (i >= n4) return;
  float4 v = reinterpret_cast<const float4*>(src)[i];
  u16x4 o;
  o[0] = f2b(v.x); o[1] = f2b(v.y); o[2] = f2b(v.z); o[3] = f2b(v.w);
  reinterpret_cast<u16x4*>(dst)[i] = o;
}

// wqkvb rows: [0,2048)=wq, [2048,4096)=wk*0.125 (folds softmax scale), [4096,6144)=wv
__global__ void k_build_wqkv(const float* __restrict__ wq, const float* __restrict__ wk,
                             const float* __restrict__ wv, unsigned short* __restrict__ dst) {
  int i = blockIdx.x * blockDim.x + threadIdx.x;  // 6144*2048/4 = 3145728 threads
  if (i >= 3145728) return;
  int e = i << 2;
  int row = e >> 11;
  int col = e & 2047;
  const float* src; float sc = 1.0f;
  if (row < 2048) { src = wq + ((size_t)row << 11); }
  else if (row < 4096) { src = wk + ((size_t)(row - 2048) << 11); sc = 0.125f; }
  else { src = wv + ((size_t)(row - 4096) << 11); }
  float4 v = *reinterpret_cast<const float4*>(src + col);
  u16x4 o;
  o[0] = f2b(v.x * sc); o[1] = f2b(v.y * sc); o[2] = f2b(v.z * sc); o[3] = f2b(v.w * sc);
  *reinterpret_cast<u16x4*>(dst + e) = o;
}

__global__ void k_build_bqkv(const float* __restrict__ bq, const float* __restrict__ bk,
                             const float* __restrict__ bv, float* __restrict__ dst) {
  int i = blockIdx.x * blockDim.x + threadIdx.x;
  if (i >= 6144) return;
  float v;
  if (i < 2048) v = bq[i];
  else if (i < 4096) v = bk[i - 2048] * 0.125f;
  else v = bv[i - 4096];
  dst[i] = v;
}

// relb[h][j][d] = rpe[h - j + 31][d]   (faithful to the reference's H==L broadcast quirk)
__global__ void k_build_rel(const float* __restrict__ rpe, unsigned short* __restrict__ dst) {
  int i = blockIdx.x * blockDim.x + threadIdx.x;  // 32*32*16 = 16384
  if (i >= 16384) return;
  int h = i >> 9;
  int j = (i >> 4) & 31;
  int d = (i & 15) << 2;
  const float* s = rpe + (size_t)(h - j + 31) * 64 + d;
  float4 v = *reinterpret_cast<const float4*>(s);
  u16x4 o;
  o[0] = f2b(v.x); o[1] = f2b(v.y); o[2] = f2b(v.z); o[3] = f2b(v.w);
  *reinterpret_cast<u16x4*>(dst + ((size_t)i << 2)) = o;
}

// ---------------- GEMM: C[M][N] = A[M][K] * B[N][K]^T + bias[N] ----------------
// Round-17: round-15 winner with the sync reduced to ONE barrier + ONE counted
// vmcnt per K-tile, both placed AFTER all 32 MFMAs (the round-15 vmcnt+BAR1 sat
// between the two MFMA clusters, stalling the matrix pipe on a wait cluster 2
// didn't need).
// Per K-tile t:
//   { reads bf+afL (buf t); stage A(t+2); 16 MFMA;
//     reads afH;            stage B(t+2); 16 MFMA;
//     vmcnt(4); BAR }
// RAW: at end-of-iter-t, outstanding = tile t+1 (4, staged at t-1) + tile t+2
//   (4, staged at t) = 8 -> vmcnt(4) completes t+1 exactly; BAR makes it
//   block-wide before iter t+1's reads (sched_barrier pins them below).
//   Tail: vmcnt(0) at t=NT-2, nothing at t=NT-1.
// WAR: stage at iter t+1 targets slot t%3, whose readers (iter t) completed
//   before iter-t's MFMAs (lgkm-waited) -> before BAR(t). Safe.
//
// XOR-swizzled LDS (proven): row-major [256][32] ushort per buf, 16B slot
// within each 64B row XORed slot' = s ^ ((row>>1)&3); staging keeps 64B-line
// coalescing (lane col-slot = (tid&3)^((tid>>3)&3)); ds_read slot =
// q ^ ((fr>>1)&3) -> 0 bank conflicts measured.

template <int OUT_F32>
__global__ __launch_bounds__(512, 1)
void k_gemm256(const unsigned short* __restrict__ A,
               const unsigned short* __restrict__ B,
               const float* __restrict__ bias,
               void* __restrict__ Cptr,
               int M, int N, int K)
{
  __shared__ __align__(16) unsigned short As[3][8192];
  __shared__ __align__(16) unsigned short Bs[3][8192];

  // bijective XCD swizzle, bm-major
  const int nbn = N >> 8;
  const int cpx = gridDim.x >> 3;
  const int orig = blockIdx.x;
  const int wg = (orig & 7) * cpx + (orig >> 3);
  const int bm = wg / nbn;
  const int bn = wg % nbn;

  const int tid = threadIdx.x;
  const int lane = tid & 63;
  const int wid = tid >> 6;
  const int wr = wid >> 2;   // 0..1  (m-half)
  const int wc = wid & 3;    // 0..3  (64-col strip)

  // staging: chunk c=tid -> row tid>>2 (0..127), chunk c+512 -> row+128.
  const int rs = tid >> 2;
  const int cs = ((tid & 3) ^ ((tid >> 3) & 3)) << 3;
  const unsigned short* agA0 = A + (size_t)(bm * 256 + rs) * K + cs;
  const unsigned short* agA1 = agA0 + (size_t)128 * K;
  const unsigned short* agB0 = B + (size_t)(bn * 256 + rs) * K + cs;
  const unsigned short* agB1 = agB0 + (size_t)128 * K;
  const int ldst = tid * 8;

  // fragment read offsets (ushort index inside one 8192-ushort matrix-buf)
  const int fr = lane & 15;
  const int q  = lane >> 4;                       // k-slot 0..3
  const int sx = q ^ ((fr >> 1) & 3);             // swizzled slot (lane constant)
  const int rbase = fr * 32 + sx * 8;
  const int aOff = wr * 4096 + rbase;             // + m*512, m=0..7
  const int bOff = wc * 2048 + rbase;             // + n*512, n=0..3

  f32x4 acc[8][4] = {};
  const int NT = K >> 5;   // 64 K-tiles

  // prologue: stage tiles 0,1 into bufs 0,1
#pragma unroll
  for (int pf = 0; pf < 2; ++pf) {
    const int kof = pf << 5;
    gload_lds16(agA0 + kof, &As[pf][ldst]);
    gload_lds16(agA1 + kof, &As[pf][ldst + 4096]);
    gload_lds16(agB0 + kof, &Bs[pf][ldst]);
    gload_lds16(agB1 + kof, &Bs[pf][ldst + 4096]);
  }
  asm volatile("s_waitcnt vmcnt(4)" ::: "memory");   // tile 0 landed
  asm volatile("s_barrier" ::: "memory");

  int rb = 0;   // buf of tile t
  int sb = 2;   // buf of tile t+2
  for (int t = 0; t < NT; ++t) {
    const unsigned short* ab = &As[rb][0];
    const unsigned short* bb = &Bs[rb][0];
    const bool st = (t + 2) < NT;               // uniform
    const int kof = (t + 2) << 5;

    // reads bf + afL (buf t, valid since previous iter's vmcnt+BAR)
    bf16x8 afL[4], bf[4];
#pragma unroll
    for (int n = 0; n < 4; ++n)
      bf[n] = *reinterpret_cast<const bf16x8*>(bb + bOff + n * 512);
#pragma unroll
    for (int m = 0; m < 4; ++m)
      afL[m] = *reinterpret_cast<const bf16x8*>(ab + aOff + m * 512);
    if (st) {
      gload_lds16(agA0 + kof, &As[sb][ldst]);
      gload_lds16(agA1 + kof, &As[sb][ldst + 4096]);
    }
    __builtin_amdgcn_s_setprio(1);
#pragma unroll
    for (int m = 0; m < 4; ++m)
#pragma unroll
      for (int n = 0; n < 4; ++n)
        acc[m][n] = __builtin_amdgcn_mfma_f32_16x16x32_bf16(afL[m], bf[n], acc[m][n], 0, 0, 0);
    __builtin_amdgcn_s_setprio(0);

    // reads afH, stage B(t+2), second MFMA cluster
    bf16x8 afH[4];
#pragma unroll
    for (int m = 0; m < 4; ++m)
      afH[m] = *reinterpret_cast<const bf16x8*>(ab + aOff + (4 + m) * 512);
    if (st) {
      gload_lds16(agB0 + kof, &Bs[sb][ldst]);
      gload_lds16(agB1 + kof, &Bs[sb][ldst + 4096]);
    }
    __builtin_amdgcn_s_setprio(1);
#pragma unroll
    for (int m = 0; m < 4; ++m)
#pragma unroll
      for (int n = 0; n < 4; ++n)
        acc[4 + m][n] = __builtin_amdgcn_mfma_f32_16x16x32_bf16(afH[m], bf[n], acc[4 + m][n], 0, 0, 0);
    __builtin_amdgcn_s_setprio(0);

    // single sync point per K-tile, after all MFMAs
    if (t < NT - 2)       asm volatile("s_waitcnt vmcnt(4)" ::: "memory");
    else if (t == NT - 2) asm volatile("s_waitcnt vmcnt(0)" ::: "memory");
    __builtin_amdgcn_sched_barrier(0);
    asm volatile("s_barrier" ::: "memory");     // tile t+1 landed block-wide + WAR drain
    __builtin_amdgcn_sched_barrier(0);

    rb = (rb == 2) ? 0 : rb + 1;
    sb = (sb == 2) ? 0 : sb + 1;
  }

  // epilogue: C/D layout col = lane&15, row = (lane>>4)*4 + reg
  const int rBase = bm * 256 + wr * 128 + (q << 2);
  const int cBase = bn * 256 + wc * 64 + fr;
#pragma unroll
  for (int n = 0; n < 4; ++n) {
    const int col = cBase + n * 16;
    const float bv = bias[col];
#pragma unroll
    for (int m = 0; m < 8; ++m) {
      const int row = rBase + m * 16;
#pragma unroll
      for (int r = 0; r < 4; ++r) {
        float v = acc[m][n][r] + bv;
        if (OUT_F32) {
          reinterpret_cast<float*>(Cptr)[(size_t)(row + r) * N + col] = v;
        } else {
          reinterpret_cast<unsigned short*>(Cptr)[(size_t)(row + r) * N + col] = f2b(v);
        }
      }
    }
  }
}

// ---------------- MFMA attention: one WAVE per (b,h), 4 waves/block ----------------
// (round-16 winner, unchanged) Per wave: Q[32,64], KR[32,64] (k_scaled + rel,
// bf16), V^T[64,32] staged in a private LDS region (no cross-wave sharing ->
// ZERO barriers; lgkmcnt fences at the two write->read handoffs).
//  QK^T: S = Q·KR^T (GEMM A·B^T frag pattern); softmax in-register via shfl_xor
//  (row i lives in 16 lanes x 2 n-frags); P (normalized, bf16) -> pS;
//  PV: ctx = P·V = A·(V^T)^T, K=32.

__global__ __launch_bounds__(256)
void k_attn(const unsigned short* __restrict__ qkv,
            const unsigned short* __restrict__ relb,
            unsigned short* __restrict__ ctx)
{
  __shared__ __align__(16) unsigned short qS[4][32 * 72];
  __shared__ __align__(16) unsigned short krS[4][32 * 72];
  __shared__ __align__(16) unsigned short vTS[4][64 * 40];
  __shared__ __align__(16) unsigned short pS[4][32 * 40];

  const int w = threadIdx.x >> 6;
  const int lane = threadIdx.x & 63;
  const int b = blockIdx.x >> 3;
  const int h = ((blockIdx.x & 7) << 2) + w;

  const int r = lane >> 1;
  const int d0 = (lane & 1) << 5;
  const unsigned short* base = qkv + (size_t)(b * 32 + r) * 6144 + h * 64 + d0;
  const unsigned short* relp = relb + (((size_t)(h * 32 + r)) << 6) + d0;

  u16x8 uq[4], uk[4], uv[4], ur[4];
#pragma unroll
  for (int c = 0; c < 4; ++c) {
    uq[c] = *reinterpret_cast<const u16x8*>(base + 8 * c);
    uk[c] = *reinterpret_cast<const u16x8*>(base + 2048 + 8 * c);
    uv[c] = *reinterpret_cast<const u16x8*>(base + 4096 + 8 * c);
    ur[c] = *reinterpret_cast<const u16x8*>(relp + 8 * c);
  }
#pragma unroll
  for (int c = 0; c < 4; ++c) {
    *reinterpret_cast<u16x8*>(&qS[w][r * 72 + d0 + 8 * c]) = uq[c];
    u16x8 kr;
#pragma unroll
    for (int e = 0; e < 8; ++e) kr[e] = f2b(b2f(uk[c][e]) + b2f(ur[c][e]));
    *reinterpret_cast<u16x8*>(&krS[w][r * 72 + d0 + 8 * c]) = kr;
#pragma unroll
    for (int e = 0; e < 8; ++e) vTS[w][(d0 + 8 * c + e) * 40 + r] = uv[c][e];
  }
  asm volatile("s_waitcnt lgkmcnt(0)" ::: "memory");
  __builtin_amdgcn_sched_barrier(0);

  const int fr16 = lane & 15;
  const int qq = lane >> 4;
  f32x4 accs[2][2] = {};
#pragma unroll
  for (int ks = 0; ks < 2; ++ks) {
    bf16x8 aq[2], bk[2];
#pragma unroll
    for (int m = 0; m < 2; ++m)
      aq[m] = *reinterpret_cast<const bf16x8*>(&qS[w][(16 * m + fr16) * 72 + 32 * ks + qq * 8]);
#pragma unroll
    for (int n = 0; n < 2; ++n)
      bk[n] = *reinterpret_cast<const bf16x8*>(&krS[w][(16 * n + fr16) * 72 + 32 * ks + qq * 8]);
#pragma unroll
    for (int m = 0; m < 2; ++m)
#pragma unroll
      for (int n = 0; n < 2; ++n)
        accs[m][n] = __builtin_amdgcn_mfma_f32_16x16x32_bf16(aq[m], bk[n], accs[m][n], 0, 0, 0);
  }

#pragma unroll
  for (int m = 0; m < 2; ++m) {
#pragma unroll
    for (int rr = 0; rr < 4; ++rr) {
      float a0 = accs[m][0][rr], a1 = accs[m][1][rr];
      float mx = fmaxf(a0, a1);
      mx = fmaxf(mx, __shfl_xor(mx, 1));
      mx = fmaxf(mx, __shfl_xor(mx, 2));
      mx = fmaxf(mx, __shfl_xor(mx, 4));
      mx = fmaxf(mx, __shfl_xor(mx, 8));
      float p0 = __expf(a0 - mx), p1 = __expf(a1 - mx);
      float sm = p0 + p1;
      sm += __shfl_xor(sm, 1);
      sm += __shfl_xor(sm, 2);
      sm += __shfl_xor(sm, 4);
      sm += __shfl_xor(sm, 8);
      const float inv = 1.0f / sm;
      const int i = 16 * m + qq * 4 + rr;
      pS[w][i * 40 + fr16]      = f2b(p0 * inv);
      pS[w][i * 40 + 16 + fr16] = f2b(p1 * inv);
    }
  }
  asm volatile("s_waitcnt lgkmcnt(0)" ::: "memory");
  __builtin_amdgcn_sched_barrier(0);

  bf16x8 ap[2], bv[4];
#pragma unroll
  for (int m = 0; m < 2; ++m)
    ap[m] = *reinterpret_cast<const bf16x8*>(&pS[w][(16 * m + fr16) * 40 + qq * 8]);
#pragma unroll
  for (int n = 0; n < 4; ++n)
    bv[n] = *reinterpret_cast<const bf16x8*>(&vTS[w][(16 * n + fr16) * 40 + qq * 8]);
  f32x4 acco[2][4] = {};
#pragma unroll
  for (int m = 0; m < 2; ++m)
#pragma unroll
    for (int n = 0; n < 4; ++n)
      acco[m][n] = __builtin_amdgcn_mfma_f32_16x16x32_bf16(ap[m], bv[n], acco[m][n], 0, 0, 0);

#pragma unroll
  for (int m = 0; m < 2; ++m) {
#pragma unroll
    for (int rr = 0; rr < 4; ++rr) {
      const int i = 16 * m + qq * 4 + rr;
      unsigned short* orow = ctx + (size_t)(b * 32 + i) * 2048 + h * 64;
#pragma unroll
      for (int n = 0; n < 4; ++n)
        orow[16 * n + fr16] = f2b(acco[m][n][rr]);
    }
  }
}

// ---------------- launch ----------------

extern "C" void kernel_launch(void* const* d_in, const int* in_sizes, int n_in,
                              void* d_out, int out_size, void* d_ws, size_t ws_size,
                              hipStream_t stream) {
  const float* x   = (const float*)d_in[0];
  const float* wq  = (const float*)d_in[1];
  const float* bq  = (const float*)d_in[2];
  const float* wk  = (const float*)d_in[3];
  const float* bk  = (const float*)d_in[4];
  const float* wv  = (const float*)d_in[5];
  const float* bv  = (const float*)d_in[6];
  const float* wo  = (const float*)d_in[7];
  const float* bo  = (const float*)d_in[8];
  const float* rpe = (const float*)d_in[9];

  char* ws = (char*)d_ws;
  unsigned short* xb    = (unsigned short*)(ws);
  unsigned short* wqkvb = (unsigned short*)(ws + 67108864);
  unsigned short* wob   = (unsigned short*)(ws + 67108864 + 25165824);
  unsigned short* qkvb  = (unsigned short*)(ws + 67108864 + 25165824 + 8388608);
  float*          bqkv  = (float*)(ws + 67108864 + 25165824 + 8388608 + 201326592);
  unsigned short* relb  = (unsigned short*)(ws + 67108864 + 25165824 + 8388608 + 201326592 + 24576);

  k_cast_f32_bf16<<<32768, 256, 0, stream>>>(x, xb, 8388608);          // 16384*2048/4
  k_build_wqkv<<<12288, 256, 0, stream>>>(wq, wk, wv, wqkvb);
  k_cast_f32_bf16<<<4096, 256, 0, stream>>>(wo, wob, 1048576);         // 2048*2048/4
  k_build_bqkv<<<24, 256, 0, stream>>>(bq, bk, bv, bqkv);
  k_build_rel<<<64, 256, 0, stream>>>(rpe, relb);

  // QKV projection: grid 64x24=1536 (%8==0)
  k_gemm256<0><<<(16384 / 256) * (6144 / 256), 512, 0, stream>>>(
      xb, wqkvb, bqkv, qkvb, 16384, 6144, 2048);

  // MFMA attention -> ctx (reuses xb buffer); 4096 blocks, wave per (b,h)
  k_attn<<<4096, 256, 0, stream>>>(qkvb, relb, xb);

  // output projection: grid 64x8=512 (%8==0)
  k_gemm256<1><<<(16384 / 256) * (2048 / 256), 512, 0, stream>>>(
      xb, wob, bo, (float*)d_out, 16384, 2048, 2048);
}

// Round 18
// 703.625 us; speedup vs baseline: 1.1848x; 1.0014x over previous
//
#include <hip/hip_runtime.h>
#include <hip/hip_bf16.h>
#include <stdint.h>

// B=512 L=32 E=2048 H=32 D=64 ; M = B*L = 16384 ; K = 2048 ; Nqkv = 6144
typedef __bf16 bf16x8 __attribute__((ext_vector_type(8)));
typedef float f32x4 __attribute__((ext_vector_type(4)));
typedef unsigned short u16x8 __attribute__((ext_vector_type(8)));
typedef unsigned short u16x4 __attribute__((ext_vector_type(4)));

#define G_AS __attribute__((address_space(1)))
#define L_AS __attribute__((address_space(3)))

__device__ __forceinline__ void gload_lds16(const void* g, void* l) {
  __builtin_amdgcn_global_load_lds((G_AS void*)g, (L_AS void*)l, 16, 0, 0);
}

__device__ __forceinline__ float b2f(unsigned short u) {
  union { float f; unsigned int i; } cv;
  cv.i = ((unsigned int)u) << 16;
  return cv.f;
}

__device__ __forceinline__ unsigned short f2b(float f) {
  unsigned int u = __float_as_uint(f);
  unsigned int r = u + 0x7FFFu + ((u >> 16) & 1u);  // RNE (inputs are non-NaN)
  return (unsigned short)(r >> 16);
}

// ---------------- cast / pack kernels ----------------

__global__ void k_cast_f32_bf16(const float* __restrict__ src,
                                unsigned short* __restrict__ dst, int n4) {
  int i = blockIdx.x * blockDim.x + threadIdx.x;
  if (i >= n4) return;
  float4 v = reinterpret_cast<const float4*>(src)[i];
  u16x4 o;
  o[0] = f2b(v.x); o[1] = f2b(v.y); o[2] = f2b(v.z); o[3] = f2b(v.w);
  reinterpret_cast<u16x4*>(dst)[i] = o;
}

// wqkvb rows: [0,2048)=wq, [2048,4096)=wk*0.125 (folds softmax scale), [4096,6144)=wv
__global__ void k_build_wqkv(const float* __restrict__ wq, const float* __restrict__ wk,
                             const float* __restrict__ wv, unsigned short* __restrict__ dst) {
  int i = blockIdx.x * blockDim.x + threadIdx.x;  // 6144*2048/4 = 3145728 threads
  if (i >= 3145728) return;
  int e = i << 2;
  int row = e >> 11;
  int col = e & 2047;
  const float* src; float sc = 1.0f;
  if (row < 2048) { src = wq + ((size_t)row << 11); }
  else if (row < 4096) { src = wk + ((size_t)(row - 2048) << 11); sc = 0.125f; }
  else { src = wv + ((size_t)(row - 4096) << 11); }
  float4 v = *reinterpret_cast<const float4*>(src + col);
  u16x4 o;
  o[0] = f2b(v.x * sc); o[1] = f2b(v.y * sc); o[2] = f2b(v.z * sc); o[3] = f2b(v.w * sc);
  *reinterpret_cast<u16x4*>(dst + e) = o;
}

__global__ void k_build_bqkv(const float* __restrict__ bq, const float* __restrict__ bk,
                             const float* __restrict__ bv, float* __restrict__ dst) {
  int i = blockIdx.x * blockDim.x + threadIdx.x;
  if (i >= 6144) return;
  float v;
  if (i < 2048) v = bq[i];
  else if (i < 4096) v = bk[i - 2048] * 0.125f;
  else v = bv[i - 4096];
  dst[i] = v;
}

// relb[h][j][d] = rpe[h - j + 31][d]   (faithful to the reference's H==L broadcast quirk)
__global__ void k_build_rel(const float* __restrict__ rpe, unsigned short* __restrict__ dst) {
  int i = blockIdx.x * blockDim.x + threadIdx.x;  // 32*32*16 = 16384
  if (i >= 16384) return;
  int h = i >> 9;
  int j = (i >> 4) & 31;
  int d = (i & 15) << 2;
  const float* s = rpe + (size_t)(h - j + 31) * 64 + d;
  float4 v = *reinterpret_cast<const float4*>(s);
  u16x4 o;
  o[0] = f2b(v.x); o[1] = f2b(v.y); o[2] = f2b(v.z); o[3] = f2b(v.w);
  *reinterpret_cast<u16x4*>(dst + ((size_t)i << 2)) = o;
}

// ---------------- GEMM: C[M][N] = A[M][K] * B[N][K]^T + bias[N] ----------------
// Round-18: BK 32 -> 64 so ONE barrier + ONE vmcnt cover 64 MFMAs (was 32).
// 32 sync points per K=2048 instead of 64 — continuing the barrier-reduction
// trajectory that won rounds 15/17 (472->459->448 us).
// 2-buffer LDS ring (2 bufs x 32 KiB x 2 matrices = 128 KiB), lookahead 1.
//
// Per K-tile t (64-wide):
//   stage A(t+1) (4 gloads)           [WAR: buf (t+1)&1 drained at t-1's BAR]
//   read bf[4][2] + af[4][2] (16 b128, buf t valid since t-1's vmcnt+BAR)
//   32 MFMA (m0-3 x n0-3 x ks0-1, setprio)
//   read af[4][2] (m4-7, 8 b128) ; stage B(t+1) (4 gloads)
//   32 MFMA (m4-7)
//   vmcnt(0); BAR   [tile t+1's 8 loads drained; issue distance ~1 tile (A),
//                    ~1/2 tile (B) >= L2/L3-warm latency]   (t=NT-1: none)
//
// XOR-swizzled LDS, 8 slots/row: row-major [256][64] ushort per buf; 16B slot
// slot' = slot ^ (row&7).
//  * staging: linear gload_lds dest chunk c = row*8+slot'; lane's global col
//    slot = (tid&7)^((tid>>3)&7) -> 8 lanes cover ONE contiguous 128B line
//    (permuted within) => coalescing preserved.
//  * frag reads: slot = ks*4+q -> slot' = (ks*4+q)^(fr&7); per 16-lane phase
//    each 4-bank group gets 2 lanes => 2-way (free). ks=1 offset = ks0 ^ 32.

template <int OUT_F32>
__global__ __launch_bounds__(512, 1)
void k_gemm256(const unsigned short* __restrict__ A,
               const unsigned short* __restrict__ B,
               const float* __restrict__ bias,
               void* __restrict__ Cptr,
               int M, int N, int K)
{
  __shared__ __align__(16) unsigned short As[2][16384];
  __shared__ __align__(16) unsigned short Bs[2][16384];

  // bijective XCD swizzle, bm-major
  const int nbn = N >> 8;
  const int cpx = gridDim.x >> 3;
  const int orig = blockIdx.x;
  const int wg = (orig & 7) * cpx + (orig >> 3);
  const int bm = wg / nbn;
  const int bn = wg % nbn;

  const int tid = threadIdx.x;
  const int lane = tid & 63;
  const int wid = tid >> 6;
  const int wr = wid >> 2;   // 0..1  (m-half)
  const int wc = wid & 3;    // 0..3  (64-col strip)

  // staging: thread covers rows r0+64j (j=0..3), chunk c = tid + 512j
  const int r0 = tid >> 3;                                // 0..63
  const int cs = ((tid & 7) ^ ((tid >> 3) & 7)) << 3;     // swizzled global col
  const unsigned short* agA = A + (size_t)(bm * 256 + r0) * K + cs;
  const unsigned short* agB = B + (size_t)(bn * 256 + r0) * K + cs;
  const int ldst = tid * 8;   // ushort offset of chunk tid; +4096 per j

  // fragment read offsets (ushort index inside one 16384-ushort matrix-buf)
  const int fr = lane & 15;
  const int q  = lane >> 4;                       // k-quarter 0..3
  const int sx0 = q ^ (fr & 7);                   // swizzled slot, ks=0
  const int aBase = (wr * 128 + fr) * 64 + sx0 * 8;   // + m*1024, ^32 for ks=1
  const int bBase = (wc * 64 + fr) * 64 + sx0 * 8;    // + n*1024, ^32 for ks=1

  f32x4 acc[8][4] = {};
  const int NT = K >> 6;   // 32 K-tiles of 64

  // prologue: stage tile 0 into buf 0 (A then B, 8 gloads), drain, barrier
#pragma unroll
  for (int j = 0; j < 4; ++j)
    gload_lds16(agA + (size_t)(64 * j) * K, &As[0][ldst + 4096 * j]);
#pragma unroll
  for (int j = 0; j < 4; ++j)
    gload_lds16(agB + (size_t)(64 * j) * K, &Bs[0][ldst + 4096 * j]);
  asm volatile("s_waitcnt vmcnt(0)" ::: "memory");
  asm volatile("s_barrier" ::: "memory");

  for (int t = 0; t < NT; ++t) {
    const int rb = t & 1;
    const int sb = rb ^ 1;
    const unsigned short* ab = &As[rb][0];
    const unsigned short* bb = &Bs[rb][0];
    const bool st = (t + 1) < NT;               // uniform
    const int kof = (t + 1) << 6;

    // stage A(t+1) early (hidden under both MFMA clusters)
    if (st) {
#pragma unroll
      for (int j = 0; j < 4; ++j)
        gload_lds16(agA + (size_t)(64 * j) * K + kof, &As[sb][ldst + 4096 * j]);
    }

    // reads: bf[n][ks] + afL[m][ks]  (buf t, valid)
    bf16x8 bf[4][2], af[4][2];
#pragma unroll
    for (int n = 0; n < 4; ++n) {
      bf[n][0] = *reinterpret_cast<const bf16x8*>(bb + (bBase + n * 1024));
      bf[n][1] = *reinterpret_cast<const bf16x8*>(bb + ((bBase + n * 1024) ^ 32));
    }
#pragma unroll
    for (int m = 0; m < 4; ++m) {
      af[m][0] = *reinterpret_cast<const bf16x8*>(ab + (aBase + m * 1024));
      af[m][1] = *reinterpret_cast<const bf16x8*>(ab + ((aBase + m * 1024) ^ 32));
    }
    __builtin_amdgcn_s_setprio(1);
#pragma unroll
    for (int ks = 0; ks < 2; ++ks)
#pragma unroll
      for (int m = 0; m < 4; ++m)
#pragma unroll
        for (int n = 0; n < 4; ++n)
          acc[m][n] = __builtin_amdgcn_mfma_f32_16x16x32_bf16(af[m][ks], bf[n][ks], acc[m][n], 0, 0, 0);
    __builtin_amdgcn_s_setprio(0);

    // reads: afH (m4-7) ; stage B(t+1)
    bf16x8 afH[4][2];
#pragma unroll
    for (int m = 0; m < 4; ++m) {
      afH[m][0] = *reinterpret_cast<const bf16x8*>(ab + (aBase + (4 + m) * 1024));
      afH[m][1] = *reinterpret_cast<const bf16x8*>(ab + ((aBase + (4 + m) * 1024) ^ 32));
    }
    if (st) {
#pragma unroll
      for (int j = 0; j < 4; ++j)
        gload_lds16(agB + (size_t)(64 * j) * K + kof, &Bs[sb][ldst + 4096 * j]);
    }
    __builtin_amdgcn_s_setprio(1);
#pragma unroll
    for (int ks = 0; ks < 2; ++ks)
#pragma unroll
      for (int m = 0; m < 4; ++m)
#pragma unroll
        for (int n = 0; n < 4; ++n)
          acc[4 + m][n] = __builtin_amdgcn_mfma_f32_16x16x32_bf16(afH[m][ks], bf[n][ks], acc[4 + m][n], 0, 0, 0);
    __builtin_amdgcn_s_setprio(0);

    // single sync point per 64-wide K-tile
    if (st) {
      asm volatile("s_waitcnt vmcnt(0)" ::: "memory");
      __builtin_amdgcn_sched_barrier(0);
      asm volatile("s_barrier" ::: "memory");   // tile t+1 landed + WAR drain
      __builtin_amdgcn_sched_barrier(0);
    }
  }

  // epilogue: C/D layout col = lane&15, row = (lane>>4)*4 + reg
  const int rBase = bm * 256 + wr * 128 + (q << 2);
  const int cBase = bn * 256 + wc * 64 + fr;
#pragma unroll
  for (int n = 0; n < 4; ++n) {
    const int col = cBase + n * 16;
    const float bv = bias[col];
#pragma unroll
    for (int m = 0; m < 8; ++m) {
      const int row = rBase + m * 16;
#pragma unroll
      for (int r = 0; r < 4; ++r) {
        float v = acc[m][n][r] + bv;
        if (OUT_F32) {
          reinterpret_cast<float*>(Cptr)[(size_t)(row + r) * N + col] = v;
        } else {
          reinterpret_cast<unsigned short*>(Cptr)[(size_t)(row + r) * N + col] = f2b(v);
        }
      }
    }
  }
}

// ---------------- MFMA attention: one WAVE per (b,h), 4 waves/block ----------------
// (round-16 winner, unchanged)

__global__ __launch_bounds__(256)
void k_attn(const unsigned short* __restrict__ qkv,
            const unsigned short* __restrict__ relb,
            unsigned short* __restrict__ ctx)
{
  __shared__ __align__(16) unsigned short qS[4][32 * 72];
  __shared__ __align__(16) unsigned short krS[4][32 * 72];
  __shared__ __align__(16) unsigned short vTS[4][64 * 40];
  __shared__ __align__(16) unsigned short pS[4][32 * 40];

  const int w = threadIdx.x >> 6;
  const int lane = threadIdx.x & 63;
  const int b = blockIdx.x >> 3;
  const int h = ((blockIdx.x & 7) << 2) + w;

  const int r = lane >> 1;
  const int d0 = (lane & 1) << 5;
  const unsigned short* base = qkv + (size_t)(b * 32 + r) * 6144 + h * 64 + d0;
  const unsigned short* relp = relb + (((size_t)(h * 32 + r)) << 6) + d0;

  u16x8 uq[4], uk[4], uv[4], ur[4];
#pragma unroll
  for (int c = 0; c < 4; ++c) {
    uq[c] = *reinterpret_cast<const u16x8*>(base + 8 * c);
    uk[c] = *reinterpret_cast<const u16x8*>(base + 2048 + 8 * c);
    uv[c] = *reinterpret_cast<const u16x8*>(base + 4096 + 8 * c);
    ur[c] = *reinterpret_cast<const u16x8*>(relp + 8 * c);
  }
#pragma unroll
  for (int c = 0; c < 4; ++c) {
    *reinterpret_cast<u16x8*>(&qS[w][r * 72 + d0 + 8 * c]) = uq[c];
    u16x8 kr;
#pragma unroll
    for (int e = 0; e < 8; ++e) kr[e] = f2b(b2f(uk[c][e]) + b2f(ur[c][e]));
    *reinterpret_cast<u16x8*>(&krS[w][r * 72 + d0 + 8 * c]) = kr;
#pragma unroll
    for (int e = 0; e < 8; ++e) vTS[w][(d0 + 8 * c + e) * 40 + r] = uv[c][e];
  }
  asm volatile("s_waitcnt lgkmcnt(0)" ::: "memory");
  __builtin_amdgcn_sched_barrier(0);

  const int fr16 = lane & 15;
  const int qq = lane >> 4;
  f32x4 accs[2][2] = {};
#pragma unroll
  for (int ks = 0; ks < 2; ++ks) {
    bf16x8 aq[2], bk[2];
#pragma unroll
    for (int m = 0; m < 2; ++m)
      aq[m] = *reinterpret_cast<const bf16x8*>(&qS[w][(16 * m + fr16) * 72 + 32 * ks + qq * 8]);
#pragma unroll
    for (int n = 0; n < 2; ++n)
      bk[n] = *reinterpret_cast<const bf16x8*>(&krS[w][(16 * n + fr16) * 72 + 32 * ks + qq * 8]);
#pragma unroll
    for (int m = 0; m < 2; ++m)
#pragma unroll
      for (int n = 0; n < 2; ++n)
        accs[m][n] = __builtin_amdgcn_mfma_f32_16x16x32_bf16(aq[m], bk[n], accs[m][n], 0, 0, 0);
  }

#pragma unroll
  for (int m = 0; m < 2; ++m) {
#pragma unroll
    for (int rr = 0; rr < 4; ++rr) {
      float a0 = accs[m][0][rr], a1 = accs[m][1][rr];
      float mx = fmaxf(a0, a1);
      mx = fmaxf(mx, __shfl_xor(mx, 1));
      mx = fmaxf(mx, __shfl_xor(mx, 2));
      mx = fmaxf(mx, __shfl_xor(mx, 4));
      mx = fmaxf(mx, __shfl_xor(mx, 8));
      float p0 = __expf(a0 - mx), p1 = __expf(a1 - mx);
      float sm = p0 + p1;
      sm += __shfl_xor(sm, 1);
      sm += __shfl_xor(sm, 2);
      sm += __shfl_xor(sm, 4);
      sm += __shfl_xor(sm, 8);
      const float inv = 1.0f / sm;
      const int i = 16 * m + qq * 4 + rr;
      pS[w][i * 40 + fr16]      = f2b(p0 * inv);
      pS[w][i * 40 + 16 + fr16] = f2b(p1 * inv);
    }
  }
  asm volatile("s_waitcnt lgkmcnt(0)" ::: "memory");
  __builtin_amdgcn_sched_barrier(0);

  bf16x8 ap[2], bv[4];
#pragma unroll
  for (int m = 0; m < 2; ++m)
    ap[m] = *reinterpret_cast<const bf16x8*>(&pS[w][(16 * m + fr16) * 40 + qq * 8]);
#pragma unroll
  for (int n = 0; n < 4; ++n)
    bv[n] = *reinterpret_cast<const bf16x8*>(&vTS[w][(16 * n + fr16) * 40 + qq * 8]);
  f32x4 acco[2][4] = {};
#pragma unroll
  for (int m = 0; m < 2; ++m)
#pragma unroll
    for (int n = 0; n < 4; ++n)
      acco[m][n] = __builtin_amdgcn_mfma_f32_16x16x32_bf16(ap[m], bv[n], acco[m][n], 0, 0, 0);

#pragma unroll
  for (int m = 0; m < 2; ++m) {
#pragma unroll
    for (int rr = 0; rr < 4; ++rr) {
      const int i = 16 * m + qq * 4 + rr;
      unsigned short* orow = ctx + (size_t)(b * 32 + i) * 2048 + h * 64;
#pragma unroll
      for (int n = 0; n < 4; ++n)
        orow[16 * n + fr16] = f2b(acco[m][n][rr]);
    }
  }
}

// ---------------- launch ----------------

extern "C" void kernel_launch(void* const* d_in, const int* in_sizes, int n_in,
                              void* d_out, int out_size, void* d_ws, size_t ws_size,
                              hipStream_t stream) {
  const float* x   = (const float*)d_in[0];
  const float* wq  = (const float*)d_in[1];
  const float* bq  = (const float*)d_in[2];
  const float* wk  = (const float*)d_in[3];
  const float* bk  = (const float*)d_in[4];
  const float* wv  = (const float*)d_in[5];
  const float* bv  = (const float*)d_in[6];
  const float* wo  = (const float*)d_in[7];
  const float* bo  = (const float*)d_in[8];
  const float* rpe = (const float*)d_in[9];

  char* ws = (char*)d_ws;
  unsigned short* xb    = (unsigned short*)(ws);
  unsigned short* wqkvb = (unsigned short*)(ws + 67108864);
  unsigned short* wob   = (unsigned short*)(ws + 67108864 + 25165824);
  unsigned short* qkvb  = (unsigned short*)(ws + 67108864 + 25165824 + 8388608);
  float*          bqkv  = (float*)(ws + 67108864 + 25165824 + 8388608 + 201326592);
  unsigned short* relb  = (unsigned short*)(ws + 67108864 + 25165824 + 8388608 + 201326592 + 24576);

  k_cast_f32_bf16<<<32768, 256, 0, stream>>>(x, xb, 8388608);          // 16384*2048/4
  k_build_wqkv<<<12288, 256, 0, stream>>>(wq, wk, wv, wqkvb);
  k_cast_f32_bf16<<<4096, 256, 0, stream>>>(wo, wob, 1048576);         // 2048*2048/4
  k_build_bqkv<<<24, 256, 0, stream>>>(bq, bk, bv, bqkv);
  k_build_rel<<<64, 256, 0, stream>>>(rpe, relb);

  // QKV projection: grid 64x24=1536 (%8==0)
  k_gemm256<0><<<(16384 / 256) * (6144 / 256), 512, 0, stream>>>(
      xb, wqkvb, bqkv, qkvb, 16384, 6144, 2048);

  // MFMA attention -> ctx (reuses xb buffer); 4096 blocks, wave per (b,h)
  k_attn<<<4096, 256, 0, stream>>>(qkvb, relb, xb);

  // output projection: grid 64x8=512 (%8==0)
  k_gemm256<1><<<(16384 / 256) * (2048 / 256), 512, 0, stream>>>(
      xb, wob, bo, (float*)d_out, 16384, 2048, 2048);
}

// Round 19
// 702.107 us; speedup vs baseline: 1.1874x; 1.0022x over previous
//
#include <hip/hip_runtime.h>
#include <hip/hip_bf16.h>
#include <stdint.h>

// B=512 L=32 E=2048 H=32 D=64 ; M = B*L = 16384 ; K = 2048 ; Nqkv = 6144
typedef __bf16 bf16x8 __attribute__((ext_vector_type(8)));
typedef float f32x4 __attribute__((ext_vector_type(4)));
typedef float f32x16 __attribute__((ext_vector_type(16)));
typedef unsigned short u16x8 __attribute__((ext_vector_type(8)));
typedef unsigned short u16x4 __attribute__((ext_vector_type(4)));

#define G_AS __attribute__((address_space(1)))
#define L_AS __attribute__((address_space(3)))

__device__ __forceinline__ void gload_lds16(const void* g, void* l) {
  __builtin_amdgcn_global_load_lds((G_AS void*)g, (L_AS void*)l, 16, 0, 0);
}

__device__ __forceinline__ float b2f(unsigned short u) {
  union { float f; unsigned int i; } cv;
  cv.i = ((unsigned int)u) << 16;
  return cv.f;
}

__device__ __forceinline__ unsigned short f2b(float f) {
  unsigned int u = __float_as_uint(f);
  unsigned int r = u + 0x7FFFu + ((u >> 16) & 1u);  // RNE (inputs are non-NaN)
  return (unsigned short)(r >> 16);
}

// ---------------- cast / pack kernels ----------------

__global__ void k_cast_f32_bf16(const float* __restrict__ src,
                                unsigned short* __restrict__ dst, int n4) {
  int i = blockIdx.x * blockDim.x + threadIdx.x;
  if (i >= n4) return;
  float4 v = reinterpret_cast<const float4*>(src)[i];
  u16x4 o;
  o[0] = f2b(v.x); o[1] = f2b(v.y); o[2] = f2b(v.z); o[3] = f2b(v.w);
  reinterpret_cast<u16x4*>(dst)[i] = o;
}

// wqkvb rows: [0,2048)=wq, [2048,4096)=wk*0.125 (folds softmax scale), [4096,6144)=wv
__global__ void k_build_wqkv(const float* __restrict__ wq, const float* __restrict__ wk,
                             const float* __restrict__ wv, unsigned short* __restrict__ dst) {
  int i = blockIdx.x * blockDim.x + threadIdx.x;  // 6144*2048/4 = 3145728 threads
  if (i >= 3145728) return;
  int e = i << 2;
  int row = e >> 11;
  int col = e & 2047;
  const float* src; float sc = 1.0f;
  if (row < 2048) { src = wq + ((size_t)row << 11); }
  else if (row < 4096) { src = wk + ((size_t)(row - 2048) << 11); sc = 0.125f; }
  else { src = wv + ((size_t)(row - 4096) << 11); }
  float4 v = *reinterpret_cast<const float4*>(src + col);
  u16x4 o;
  o[0] = f2b(v.x * sc); o[1] = f2b(v.y * sc); o[2] = f2b(v.z * sc); o[3] = f2b(v.w * sc);
  *reinterpret_cast<u16x4*>(dst + e) = o;
}

__global__ void k_build_bqkv(const float* __restrict__ bq, const float* __restrict__ bk,
                             const float* __restrict__ bv, float* __restrict__ dst) {
  int i = blockIdx.x * blockDim.x + threadIdx.x;
  if (i >= 6144) return;
  float v;
  if (i < 2048) v = bq[i];
  else if (i < 4096) v = bk[i - 2048] * 0.125f;
  else v = bv[i - 4096];
  dst[i] = v;
}

// relb[h][j][d] = rpe[h - j + 31][d]   (faithful to the reference's H==L broadcast quirk)
__global__ void k_build_rel(const float* __restrict__ rpe, unsigned short* __restrict__ dst) {
  int i = blockIdx.x * blockDim.x + threadIdx.x;  // 32*32*16 = 16384
  if (i >= 16384) return;
  int h = i >> 9;
  int j = (i >> 4) & 31;
  int d = (i & 15) << 2;
  const float* s = rpe + (size_t)(h - j + 31) * 64 + d;
  float4 v = *reinterpret_cast<const float4*>(s);
  u16x4 o;
  o[0] = f2b(v.x); o[1] = f2b(v.y); o[2] = f2b(v.z); o[3] = f2b(v.w);
  *reinterpret_cast<u16x4*>(dst + ((size_t)i << 2)) = o;
}

// ---------------- GEMM: C[M][N] = A[M][K] * B[N][K]^T + bias[N] ----------------
// Round-19: round-17 skeleton (448 us QKV: 3-buf ring, 1 counted vmcnt(4) + 1
// barrier per BK=32 tile, XOR-swizzled LDS, XCD swizzle) with the MFMA shape
// switched 16x16x32 -> 32x32x16 (ubench ceiling 2382 vs 2075 TF, +15%; halves
// MFMA instruction count per FLOP; ds_read count unchanged at 12 b128/wave).
//   per wave 128x64 = 4m x 2n frags of 32x32 ; acc = f32x16[4][2] (128 AGPR).
//   A/B input layout (symmetric to the proven 16x16 mapping): lane holds
//   row = lane&31, k = (lane>>5)*8 + e. C/D (HW-verified m74/m101):
//   col = lane&31, row = (reg&3) + 8*(reg>>2) + 4*(lane>>5).
// Bank check under slot' = s ^ ((row>>1)&3): per 32-lane half, even rows sweep
// bank-starts {0,4,8,12} x4 lanes, odd rows 16-31 -> every bank exactly 8
// accesses per wave-b128 = theoretical minimum -> conflict-free.
// ks=1 slot = ks0-slot ^ 2 -> ushort address ^ 16.

template <int OUT_F32>
__global__ __launch_bounds__(512, 1)
void k_gemm256(const unsigned short* __restrict__ A,
               const unsigned short* __restrict__ B,
               const float* __restrict__ bias,
               void* __restrict__ Cptr,
               int M, int N, int K)
{
  __shared__ __align__(16) unsigned short As[3][8192];
  __shared__ __align__(16) unsigned short Bs[3][8192];

  // bijective XCD swizzle, bm-major
  const int nbn = N >> 8;
  const int cpx = gridDim.x >> 3;
  const int orig = blockIdx.x;
  const int wg = (orig & 7) * cpx + (orig >> 3);
  const int bm = wg / nbn;
  const int bn = wg % nbn;

  const int tid = threadIdx.x;
  const int lane = tid & 63;
  const int wid = tid >> 6;
  const int wr = wid >> 2;   // 0..1  (m-half)
  const int wc = wid & 3;    // 0..3  (64-col strip)

  // staging: chunk c=tid -> row tid>>2 (0..127), chunk c+512 -> row+128.
  const int rs = tid >> 2;
  const int cs = ((tid & 3) ^ ((tid >> 3) & 3)) << 3;
  const unsigned short* agA0 = A + (size_t)(bm * 256 + rs) * K + cs;
  const unsigned short* agA1 = agA0 + (size_t)128 * K;
  const unsigned short* agB0 = B + (size_t)(bn * 256 + rs) * K + cs;
  const unsigned short* agB1 = agB0 + (size_t)128 * K;
  const int ldst = tid * 8;

  // fragment read offsets for 32x32x16 (ushort index in one 8192-ushort buf)
  // row = {wr*128|wc*64} + frag*32 + (lane&31); slot(ks, kg=lane>>5) = ks*2+kg,
  // swizzled ^ ((lane>>1)&3) (base rows are multiples of 32 -> term lane-only).
  const int l31 = lane & 31;
  const int kg  = lane >> 5;
  const int sx0 = kg ^ ((l31 >> 1) & 3);          // slot for ks=0 (ks=1: ^2 -> addr^16)
  const int aBase = (wr * 128 + l31) * 32 + sx0 * 8;   // + mi*1024
  const int bBase = (wc * 64  + l31) * 32 + sx0 * 8;   // + ni*1024

  f32x16 acc[4][2] = {};
  const int NT = K >> 5;   // 64 K-tiles

  // prologue: stage tiles 0,1 into bufs 0,1
#pragma unroll
  for (int pf = 0; pf < 2; ++pf) {
    const int kof = pf << 5;
    gload_lds16(agA0 + kof, &As[pf][ldst]);
    gload_lds16(agA1 + kof, &As[pf][ldst + 4096]);
    gload_lds16(agB0 + kof, &Bs[pf][ldst]);
    gload_lds16(agB1 + kof, &Bs[pf][ldst + 4096]);
  }
  asm volatile("s_waitcnt vmcnt(4)" ::: "memory");   // tile 0 landed
  asm volatile("s_barrier" ::: "memory");

  int rb = 0;   // buf of tile t
  int sb = 2;   // buf of tile t+2
  for (int t = 0; t < NT; ++t) {
    const unsigned short* ab = &As[rb][0];
    const unsigned short* bb = &Bs[rb][0];
    const bool st = (t + 2) < NT;               // uniform
    const int kof = (t + 2) << 5;

    // reads: all B frags + A frags mi 0-1 ; stage A(t+2)
    bf16x8 bfr[2][2], af[2][2];
#pragma unroll
    for (int ni = 0; ni < 2; ++ni) {
      bfr[ni][0] = *reinterpret_cast<const bf16x8*>(bb + (bBase + ni * 1024));
      bfr[ni][1] = *reinterpret_cast<const bf16x8*>(bb + ((bBase + ni * 1024) ^ 16));
    }
#pragma unroll
    for (int mi = 0; mi < 2; ++mi) {
      af[mi][0] = *reinterpret_cast<const bf16x8*>(ab + (aBase + mi * 1024));
      af[mi][1] = *reinterpret_cast<const bf16x8*>(ab + ((aBase + mi * 1024) ^ 16));
    }
    if (st) {
      gload_lds16(agA0 + kof, &As[sb][ldst]);
      gload_lds16(agA1 + kof, &As[sb][ldst + 4096]);
    }
    __builtin_amdgcn_s_setprio(1);
#pragma unroll
    for (int ks = 0; ks < 2; ++ks)
#pragma unroll
      for (int mi = 0; mi < 2; ++mi)
#pragma unroll
        for (int ni = 0; ni < 2; ++ni)
          acc[mi][ni] = __builtin_amdgcn_mfma_f32_32x32x16_bf16(af[mi][ks], bfr[ni][ks], acc[mi][ni], 0, 0, 0);
    __builtin_amdgcn_s_setprio(0);

    // reads: A frags mi 2-3 ; stage B(t+2) ; second MFMA cluster
    bf16x8 afH[2][2];
#pragma unroll
    for (int mi = 0; mi < 2; ++mi) {
      afH[mi][0] = *reinterpret_cast<const bf16x8*>(ab + (aBase + (2 + mi) * 1024));
      afH[mi][1] = *reinterpret_cast<const bf16x8*>(ab + ((aBase + (2 + mi) * 1024) ^ 16));
    }
    if (st) {
      gload_lds16(agB0 + kof, &Bs[sb][ldst]);
      gload_lds16(agB1 + kof, &Bs[sb][ldst + 4096]);
    }
    __builtin_amdgcn_s_setprio(1);
#pragma unroll
    for (int ks = 0; ks < 2; ++ks)
#pragma unroll
      for (int mi = 0; mi < 2; ++mi)
#pragma unroll
        for (int ni = 0; ni < 2; ++ni)
          acc[2 + mi][ni] = __builtin_amdgcn_mfma_f32_32x32x16_bf16(afH[mi][ks], bfr[ni][ks], acc[2 + mi][ni], 0, 0, 0);
    __builtin_amdgcn_s_setprio(0);

    // single sync point per K-tile, after all MFMAs (round-17 proven)
    if (t < NT - 2)       asm volatile("s_waitcnt vmcnt(4)" ::: "memory");
    else if (t == NT - 2) asm volatile("s_waitcnt vmcnt(0)" ::: "memory");
    __builtin_amdgcn_sched_barrier(0);
    asm volatile("s_barrier" ::: "memory");     // tile t+1 landed + WAR drain
    __builtin_amdgcn_sched_barrier(0);

    rb = (rb == 2) ? 0 : rb + 1;
    sb = (sb == 2) ? 0 : sb + 1;
  }

  // epilogue: 32x32 C/D layout col = lane&31, row = (reg&3)+8*(reg>>2)+4*kg
  const int rEp = bm * 256 + wr * 128 + 4 * kg;
  const int cEp = bn * 256 + wc * 64 + l31;
#pragma unroll
  for (int ni = 0; ni < 2; ++ni) {
    const int col = cEp + ni * 32;
    const float bv = bias[col];
#pragma unroll
    for (int mi = 0; mi < 4; ++mi) {
      const int rowb = rEp + mi * 32;
#pragma unroll
      for (int reg = 0; reg < 16; ++reg) {
        const int row = rowb + (reg & 3) + 8 * (reg >> 2);
        float v = acc[mi][ni][reg] + bv;
        if (OUT_F32) {
          reinterpret_cast<float*>(Cptr)[(size_t)row * N + col] = v;
        } else {
          reinterpret_cast<unsigned short*>(Cptr)[(size_t)row * N + col] = f2b(v);
        }
      }
    }
  }
}

// ---------------- MFMA attention: one WAVE per (b,h), 4 waves/block ----------------
// (round-16 winner, unchanged)

__global__ __launch_bounds__(256)
void k_attn(const unsigned short* __restrict__ qkv,
            const unsigned short* __restrict__ relb,
            unsigned short* __restrict__ ctx)
{
  __shared__ __align__(16) unsigned short qS[4][32 * 72];
  __shared__ __align__(16) unsigned short krS[4][32 * 72];
  __shared__ __align__(16) unsigned short vTS[4][64 * 40];
  __shared__ __align__(16) unsigned short pS[4][32 * 40];

  const int w = threadIdx.x >> 6;
  const int lane = threadIdx.x & 63;
  const int b = blockIdx.x >> 3;
  const int h = ((blockIdx.x & 7) << 2) + w;

  const int r = lane >> 1;
  const int d0 = (lane & 1) << 5;
  const unsigned short* base = qkv + (size_t)(b * 32 + r) * 6144 + h * 64 + d0;
  const unsigned short* relp = relb + (((size_t)(h * 32 + r)) << 6) + d0;

  u16x8 uq[4], uk[4], uv[4], ur[4];
#pragma unroll
  for (int c = 0; c < 4; ++c) {
    uq[c] = *reinterpret_cast<const u16x8*>(base + 8 * c);
    uk[c] = *reinterpret_cast<const u16x8*>(base + 2048 + 8 * c);
    uv[c] = *reinterpret_cast<const u16x8*>(base + 4096 + 8 * c);
    ur[c] = *reinterpret_cast<const u16x8*>(relp + 8 * c);
  }
#pragma unroll
  for (int c = 0; c < 4; ++c) {
    *reinterpret_cast<u16x8*>(&qS[w][r * 72 + d0 + 8 * c]) = uq[c];
    u16x8 kr;
#pragma unroll
    for (int e = 0; e < 8; ++e) kr[e] = f2b(b2f(uk[c][e]) + b2f(ur[c][e]));
    *reinterpret_cast<u16x8*>(&krS[w][r * 72 + d0 + 8 * c]) = kr;
#pragma unroll
    for (int e = 0; e < 8; ++e) vTS[w][(d0 + 8 * c + e) * 40 + r] = uv[c][e];
  }
  asm volatile("s_waitcnt lgkmcnt(0)" ::: "memory");
  __builtin_amdgcn_sched_barrier(0);

  const int fr16 = lane & 15;
  const int qq = lane >> 4;
  f32x4 accs[2][2] = {};
#pragma unroll
  for (int ks = 0; ks < 2; ++ks) {
    bf16x8 aq[2], bk[2];
#pragma unroll
    for (int m = 0; m < 2; ++m)
      aq[m] = *reinterpret_cast<const bf16x8*>(&qS[w][(16 * m + fr16) * 72 + 32 * ks + qq * 8]);
#pragma unroll
    for (int n = 0; n < 2; ++n)
      bk[n] = *reinterpret_cast<const bf16x8*>(&krS[w][(16 * n + fr16) * 72 + 32 * ks + qq * 8]);
#pragma unroll
    for (int m = 0; m < 2; ++m)
#pragma unroll
      for (int n = 0; n < 2; ++n)
        accs[m][n] = __builtin_amdgcn_mfma_f32_16x16x32_bf16(aq[m], bk[n], accs[m][n], 0, 0, 0);
  }

#pragma unroll
  for (int m = 0; m < 2; ++m) {
#pragma unroll
    for (int rr = 0; rr < 4; ++rr) {
      float a0 = accs[m][0][rr], a1 = accs[m][1][rr];
      float mx = fmaxf(a0, a1);
      mx = fmaxf(mx, __shfl_xor(mx, 1));
      mx = fmaxf(mx, __shfl_xor(mx, 2));
      mx = fmaxf(mx, __shfl_xor(mx, 4));
      mx = fmaxf(mx, __shfl_xor(mx, 8));
      float p0 = __expf(a0 - mx), p1 = __expf(a1 - mx);
      float sm = p0 + p1;
      sm += __shfl_xor(sm, 1);
      sm += __shfl_xor(sm, 2);
      sm += __shfl_xor(sm, 4);
      sm += __shfl_xor(sm, 8);
      const float inv = 1.0f / sm;
      const int i = 16 * m + qq * 4 + rr;
      pS[w][i * 40 + fr16]      = f2b(p0 * inv);
      pS[w][i * 40 + 16 + fr16] = f2b(p1 * inv);
    }
  }
  asm volatile("s_waitcnt lgkmcnt(0)" ::: "memory");
  __builtin_amdgcn_sched_barrier(0);

  bf16x8 ap[2], bv[4];
#pragma unroll
  for (int m = 0; m < 2; ++m)
    ap[m] = *reinterpret_cast<const bf16x8*>(&pS[w][(16 * m + fr16) * 40 + qq * 8]);
#pragma unroll
  for (int n = 0; n < 4; ++n)
    bv[n] = *reinterpret_cast<const bf16x8*>(&vTS[w][(16 * n + fr16) * 40 + qq * 8]);
  f32x4 acco[2][4] = {};
#pragma unroll
  for (int m = 0; m < 2; ++m)
#pragma unroll
    for (int n = 0; n < 4; ++n)
      acco[m][n] = __builtin_amdgcn_mfma_f32_16x16x32_bf16(ap[m], bv[n], acco[m][n], 0, 0, 0);

#pragma unroll
  for (int m = 0; m < 2; ++m) {
#pragma unroll
    for (int rr = 0; rr < 4; ++rr) {
      const int i = 16 * m + qq * 4 + rr;
      unsigned short* orow = ctx + (size_t)(b * 32 + i) * 2048 + h * 64;
#pragma unroll
      for (int n = 0; n < 4; ++n)
        orow[16 * n + fr16] = f2b(acco[m][n][rr]);
    }
  }
}

// ---------------- launch ----------------

extern "C" void kernel_launch(void* const* d_in, const int* in_sizes, int n_in,
                              void* d_out, int out_size, void* d_ws, size_t ws_size,
                              hipStream_t stream) {
  const float* x   = (const float*)d_in[0];
  const float* wq  = (const float*)d_in[1];
  const float* bq  = (const float*)d_in[2];
  const float* wk  = (const float*)d_in[3];
  const float* bk  = (const float*)d_in[4];
  const float* wv  = (const float*)d_in[5];
  const float* bv  = (const float*)d_in[6];
  const float* wo  = (const float*)d_in[7];
  const float* bo  = (const float*)d_in[8];
  const float* rpe = (const float*)d_in[9];

  char* ws = (char*)d_ws;
  unsigned short* xb    = (unsigned short*)(ws);
  unsigned short* wqkvb = (unsigned short*)(ws + 67108864);
  unsigned short* wob   = (unsigned short*)(ws + 67108864 + 25165824);
  unsigned short* qkvb  = (unsigned short*)(ws + 67108864 + 25165824 + 8388608);
  float*          bqkv  = (float*)(ws + 67108864 + 25165824 + 8388608 + 201326592);
  unsigned short* relb  = (unsigned short*)(ws + 67108864 + 25165824 + 8388608 + 201326592 + 24576);

  k_cast_f32_bf16<<<32768, 256, 0, stream>>>(x, xb, 8388608);          // 16384*2048/4
  k_build_wqkv<<<12288, 256, 0, stream>>>(wq, wk, wv, wqkvb);
  k_cast_f32_bf16<<<4096, 256, 0, stream>>>(wo, wob, 1048576);         // 2048*2048/4
  k_build_bqkv<<<24, 256, 0, stream>>>(bq, bk, bv, bqkv);
  k_build_rel<<<64, 256, 0, stream>>>(rpe, relb);

  // QKV projection: grid 64x24=1536 (%8==0)
  k_gemm256<0><<<(16384 / 256) * (6144 / 256), 512, 0, stream>>>(
      xb, wqkvb, bqkv, qkvb, 16384, 6144, 2048);

  // MFMA attention -> ctx (reuses xb buffer); 4096 blocks, wave per (b,h)
  k_attn<<<4096, 256, 0, stream>>>(qkvb, relb, xb);

  // output projection: grid 64x8=512 (%8==0)
  k_gemm256<1><<<(16384 / 256) * (2048 / 256), 512, 0, stream>>>(
      xb, wob, bo, (float*)d_out, 16384, 2048, 2048);
}

// Round 20
// 702.012 us; speedup vs baseline: 1.1875x; 1.0001x over previous
//
#include <hip/hip_runtime.h>
#include <hip/hip_bf16.h>
#include <stdint.h>

// B=512 L=32 E=2048 H=32 D=64 ; M = B*L = 16384 ; K = 2048 ; Nqkv = 6144
typedef __bf16 bf16x8 __attribute__((ext_vector_type(8)));
typedef float f32x4 __attribute__((ext_vector_type(4)));
typedef float f32x16 __attribute__((ext_vector_type(16)));
typedef unsigned short u16x8 __attribute__((ext_vector_type(8)));
typedef unsigned short u16x4 __attribute__((ext_vector_type(4)));

#define G_AS __attribute__((address_space(1)))
#define L_AS __attribute__((address_space(3)))

__device__ __forceinline__ void gload_lds16(const void* g, void* l) {
  __builtin_amdgcn_global_load_lds((G_AS void*)g, (L_AS void*)l, 16, 0, 0);
}

__device__ __forceinline__ float b2f(unsigned short u) {
  union { float f; unsigned int i; } cv;
  cv.i = ((unsigned int)u) << 16;
  return cv.f;
}

__device__ __forceinline__ unsigned short f2b(float f) {
  unsigned int u = __float_as_uint(f);
  unsigned int r = u + 0x7FFFu + ((u >> 16) & 1u);  // RNE (inputs are non-NaN)
  return (unsigned short)(r >> 16);
}

// ---------------- cast / pack kernels ----------------

__global__ void k_cast_f32_bf16(const float* __restrict__ src,
                                unsigned short* __restrict__ dst, int n4) {
  int i = blockIdx.x * blockDim.x + threadIdx.x;
  if (i >= n4) return;
  float4 v = reinterpret_cast<const float4*>(src)[i];
  u16x4 o;
  o[0] = f2b(v.x); o[1] = f2b(v.y); o[2] = f2b(v.z); o[3] = f2b(v.w);
  reinterpret_cast<u16x4*>(dst)[i] = o;
}

// wqkvb rows: [0,2048)=wq, [2048,4096)=wk*0.125 (folds softmax scale), [4096,6144)=wv
__global__ void k_build_wqkv(const float* __restrict__ wq, const float* __restrict__ wk,
                             const float* __restrict__ wv, unsigned short* __restrict__ dst) {
  int i = blockIdx.x * blockDim.x + threadIdx.x;  // 6144*2048/4 = 3145728 threads
  if (i >= 3145728) return;
  int e = i << 2;
  int row = e >> 11;
  int col = e & 2047;
  const float* src; float sc = 1.0f;
  if (row < 2048) { src = wq + ((size_t)row << 11); }
  else if (row < 4096) { src = wk + ((size_t)(row - 2048) << 11); sc = 0.125f; }
  else { src = wv + ((size_t)(row - 4096) << 11); }
  float4 v = *reinterpret_cast<const float4*>(src + col);
  u16x4 o;
  o[0] = f2b(v.x * sc); o[1] = f2b(v.y * sc); o[2] = f2b(v.z * sc); o[3] = f2b(v.w * sc);
  *reinterpret_cast<u16x4*>(dst + e) = o;
}

__global__ void k_build_bqkv(const float* __restrict__ bq, const float* __restrict__ bk,
                             const float* __restrict__ bv, float* __restrict__ dst) {
  int i = blockIdx.x * blockDim.x + threadIdx.x;
  if (i >= 6144) return;
  float v;
  if (i < 2048) v = bq[i];
  else if (i < 4096) v = bk[i - 2048] * 0.125f;
  else v = bv[i - 4096];
  dst[i] = v;
}

// relb[h][j][d] = rpe[h - j + 31][d]   (faithful to the reference's H==L broadcast quirk)
__global__ void k_build_rel(const float* __restrict__ rpe, unsigned short* __restrict__ dst) {
  int i = blockIdx.x * blockDim.x + threadIdx.x;  // 32*32*16 = 16384
  if (i >= 16384) return;
  int h = i >> 9;
  int j = (i >> 4) & 31;
  int d = (i & 15) << 2;
  const float* s = rpe + (size_t)(h - j + 31) * 64 + d;
  float4 v = *reinterpret_cast<const float4*>(s);
  u16x4 o;
  o[0] = f2b(v.x); o[1] = f2b(v.y); o[2] = f2b(v.z); o[3] = f2b(v.w);
  *reinterpret_cast<u16x4*>(dst + ((size_t)i << 2)) = o;
}

// ---------------- GEMM: C[M][N] = A[M][K] * B[N][K]^T + bias[N] ----------------
// Round-20: round-19 (32x32x16 MFMA, 3-buf ring, 1 sync/tile) with the LDS
// swizzle extended by a row-bit-3 term to kill the measured 3.775e7 conflicts:
//   swz(row) = ((row>>1)&3) ^ (((row>>3)&1)<<1)
// 32x32 frag reads: rows {r, r+8, r+16, r+24} now get swz offsets {0,2,0,2} ->
// the 8 covering lanes split 2-per-bank-quad = free minimum (was 4-way).
// 16x16-era staging coalescing unaffected: the XOR permutes 16B slots WITHIN
// one 64B row-line; both chunks per thread (row, row+128) share the same swz
// (bits 1..3 of row preserved by +128). Frag base rows are multiples of 32 ->
// swz depends only on lane&31 (lane constant). ks=1 slot flip stays addr^16.

template <int OUT_F32>
__global__ __launch_bounds__(512, 1)
void k_gemm256(const unsigned short* __restrict__ A,
               const unsigned short* __restrict__ B,
               const float* __restrict__ bias,
               void* __restrict__ Cptr,
               int M, int N, int K)
{
  __shared__ __align__(16) unsigned short As[3][8192];
  __shared__ __align__(16) unsigned short Bs[3][8192];

  // bijective XCD swizzle, bm-major
  const int nbn = N >> 8;
  const int cpx = gridDim.x >> 3;
  const int orig = blockIdx.x;
  const int wg = (orig & 7) * cpx + (orig >> 3);
  const int bm = wg / nbn;
  const int bn = wg % nbn;

  const int tid = threadIdx.x;
  const int lane = tid & 63;
  const int wid = tid >> 6;
  const int wr = wid >> 2;   // 0..1  (m-half)
  const int wc = wid & 3;    // 0..3  (64-col strip)

  // staging: chunk c=tid -> row rs=tid>>2 (0..127), chunk c+512 -> row+128.
  // global col slot = (tid&3) ^ swz(rs), swz(rs)=((rs>>1)&3)^(((rs>>3)&1)<<1)
  const int rs = tid >> 2;
  const int cs = ((tid & 3) ^ ((tid >> 3) & 3) ^ (((tid >> 5) & 1) << 1)) << 3;
  const unsigned short* agA0 = A + (size_t)(bm * 256 + rs) * K + cs;
  const unsigned short* agA1 = agA0 + (size_t)128 * K;
  const unsigned short* agB0 = B + (size_t)(bn * 256 + rs) * K + cs;
  const unsigned short* agB1 = agB0 + (size_t)128 * K;
  const int ldst = tid * 8;

  // fragment read offsets for 32x32x16 (ushort index in one 8192-ushort buf)
  // row = base(mult of 32) + (lane&31); slot(ks=0) = kg ^ swz(l31); ks=1: ^16
  const int l31 = lane & 31;
  const int kg  = lane >> 5;
  const int sx0 = kg ^ ((l31 >> 1) & 3) ^ (((l31 >> 3) & 1) << 1);
  const int aBase = (wr * 128 + l31) * 32 + sx0 * 8;   // + mi*1024
  const int bBase = (wc * 64  + l31) * 32 + sx0 * 8;   // + ni*1024

  f32x16 acc[4][2] = {};
  const int NT = K >> 5;   // 64 K-tiles

  // prologue: stage tiles 0,1 into bufs 0,1
#pragma unroll
  for (int pf = 0; pf < 2; ++pf) {
    const int kof = pf << 5;
    gload_lds16(agA0 + kof, &As[pf][ldst]);
    gload_lds16(agA1 + kof, &As[pf][ldst + 4096]);
    gload_lds16(agB0 + kof, &Bs[pf][ldst]);
    gload_lds16(agB1 + kof, &Bs[pf][ldst + 4096]);
  }
  asm volatile("s_waitcnt vmcnt(4)" ::: "memory");   // tile 0 landed
  asm volatile("s_barrier" ::: "memory");

  int rb = 0;   // buf of tile t
  int sb = 2;   // buf of tile t+2
  for (int t = 0; t < NT; ++t) {
    const unsigned short* ab = &As[rb][0];
    const unsigned short* bb = &Bs[rb][0];
    const bool st = (t + 2) < NT;               // uniform
    const int kof = (t + 2) << 5;

    // reads: all B frags + A frags mi 0-1 ; stage A(t+2)
    bf16x8 bfr[2][2], af[2][2];
#pragma unroll
    for (int ni = 0; ni < 2; ++ni) {
      bfr[ni][0] = *reinterpret_cast<const bf16x8*>(bb + (bBase + ni * 1024));
      bfr[ni][1] = *reinterpret_cast<const bf16x8*>(bb + ((bBase + ni * 1024) ^ 16));
    }
#pragma unroll
    for (int mi = 0; mi < 2; ++mi) {
      af[mi][0] = *reinterpret_cast<const bf16x8*>(ab + (aBase + mi * 1024));
      af[mi][1] = *reinterpret_cast<const bf16x8*>(ab + ((aBase + mi * 1024) ^ 16));
    }
    if (st) {
      gload_lds16(agA0 + kof, &As[sb][ldst]);
      gload_lds16(agA1 + kof, &As[sb][ldst + 4096]);
    }
    __builtin_amdgcn_s_setprio(1);
#pragma unroll
    for (int ks = 0; ks < 2; ++ks)
#pragma unroll
      for (int mi = 0; mi < 2; ++mi)
#pragma unroll
        for (int ni = 0; ni < 2; ++ni)
          acc[mi][ni] = __builtin_amdgcn_mfma_f32_32x32x16_bf16(af[mi][ks], bfr[ni][ks], acc[mi][ni], 0, 0, 0);
    __builtin_amdgcn_s_setprio(0);

    // reads: A frags mi 2-3 ; stage B(t+2) ; second MFMA cluster
    bf16x8 afH[2][2];
#pragma unroll
    for (int mi = 0; mi < 2; ++mi) {
      afH[mi][0] = *reinterpret_cast<const bf16x8*>(ab + (aBase + (2 + mi) * 1024));
      afH[mi][1] = *reinterpret_cast<const bf16x8*>(ab + ((aBase + (2 + mi) * 1024) ^ 16));
    }
    if (st) {
      gload_lds16(agB0 + kof, &Bs[sb][ldst]);
      gload_lds16(agB1 + kof, &Bs[sb][ldst + 4096]);
    }
    __builtin_amdgcn_s_setprio(1);
#pragma unroll
    for (int ks = 0; ks < 2; ++ks)
#pragma unroll
      for (int mi = 0; mi < 2; ++mi)
#pragma unroll
        for (int ni = 0; ni < 2; ++ni)
          acc[2 + mi][ni] = __builtin_amdgcn_mfma_f32_32x32x16_bf16(afH[mi][ks], bfr[ni][ks], acc[2 + mi][ni], 0, 0, 0);
    __builtin_amdgcn_s_setprio(0);

    // single sync point per K-tile, after all MFMAs (round-17 proven)
    if (t < NT - 2)       asm volatile("s_waitcnt vmcnt(4)" ::: "memory");
    else if (t == NT - 2) asm volatile("s_waitcnt vmcnt(0)" ::: "memory");
    __builtin_amdgcn_sched_barrier(0);
    asm volatile("s_barrier" ::: "memory");     // tile t+1 landed + WAR drain
    __builtin_amdgcn_sched_barrier(0);

    rb = (rb == 2) ? 0 : rb + 1;
    sb = (sb == 2) ? 0 : sb + 1;
  }

  // epilogue: 32x32 C/D layout col = lane&31, row = (reg&3)+8*(reg>>2)+4*kg
  const int rEp = bm * 256 + wr * 128 + 4 * kg;
  const int cEp = bn * 256 + wc * 64 + l31;
#pragma unroll
  for (int ni = 0; ni < 2; ++ni) {
    const int col = cEp + ni * 32;
    const float bv = bias[col];
#pragma unroll
    for (int mi = 0; mi < 4; ++mi) {
      const int rowb = rEp + mi * 32;
#pragma unroll
      for (int reg = 0; reg < 16; ++reg) {
        const int row = rowb + (reg & 3) + 8 * (reg >> 2);
        float v = acc[mi][ni][reg] + bv;
        if (OUT_F32) {
          reinterpret_cast<float*>(Cptr)[(size_t)row * N + col] = v;
        } else {
          reinterpret_cast<unsigned short*>(Cptr)[(size_t)row * N + col] = f2b(v);
        }
      }
    }
  }
}

// ---------------- MFMA attention: one WAVE per (b,h), 4 waves/block ----------------
// (round-16 winner, unchanged)

__global__ __launch_bounds__(256)
void k_attn(const unsigned short* __restrict__ qkv,
            const unsigned short* __restrict__ relb,
            unsigned short* __restrict__ ctx)
{
  __shared__ __align__(16) unsigned short qS[4][32 * 72];
  __shared__ __align__(16) unsigned short krS[4][32 * 72];
  __shared__ __align__(16) unsigned short vTS[4][64 * 40];
  __shared__ __align__(16) unsigned short pS[4][32 * 40];

  const int w = threadIdx.x >> 6;
  const int lane = threadIdx.x & 63;
  const int b = blockIdx.x >> 3;
  const int h = ((blockIdx.x & 7) << 2) + w;

  const int r = lane >> 1;
  const int d0 = (lane & 1) << 5;
  const unsigned short* base = qkv + (size_t)(b * 32 + r) * 6144 + h * 64 + d0;
  const unsigned short* relp = relb + (((size_t)(h * 32 + r)) << 6) + d0;

  u16x8 uq[4], uk[4], uv[4], ur[4];
#pragma unroll
  for (int c = 0; c < 4; ++c) {
    uq[c] = *reinterpret_cast<const u16x8*>(base + 8 * c);
    uk[c] = *reinterpret_cast<const u16x8*>(base + 2048 + 8 * c);
    uv[c] = *reinterpret_cast<const u16x8*>(base + 4096 + 8 * c);
    ur[c] = *reinterpret_cast<const u16x8*>(relp + 8 * c);
  }
#pragma unroll
  for (int c = 0; c < 4; ++c) {
    *reinterpret_cast<u16x8*>(&qS[w][r * 72 + d0 + 8 * c]) = uq[c];
    u16x8 kr;
#pragma unroll
    for (int e = 0; e < 8; ++e) kr[e] = f2b(b2f(uk[c][e]) + b2f(ur[c][e]));
    *reinterpret_cast<u16x8*>(&krS[w][r * 72 + d0 + 8 * c]) = kr;
#pragma unroll
    for (int e = 0; e < 8; ++e) vTS[w][(d0 + 8 * c + e) * 40 + r] = uv[c][e];
  }
  asm volatile("s_waitcnt lgkmcnt(0)" ::: "memory");
  __builtin_amdgcn_sched_barrier(0);

  const int fr16 = lane & 15;
  const int qq = lane >> 4;
  f32x4 accs[2][2] = {};
#pragma unroll
  for (int ks = 0; ks < 2; ++ks) {
    bf16x8 aq[2], bk[2];
#pragma unroll
    for (int m = 0; m < 2; ++m)
      aq[m] = *reinterpret_cast<const bf16x8*>(&qS[w][(16 * m + fr16) * 72 + 32 * ks + qq * 8]);
#pragma unroll
    for (int n = 0; n < 2; ++n)
      bk[n] = *reinterpret_cast<const bf16x8*>(&krS[w][(16 * n + fr16) * 72 + 32 * ks + qq * 8]);
#pragma unroll
    for (int m = 0; m < 2; ++m)
#pragma unroll
      for (int n = 0; n < 2; ++n)
        accs[m][n] = __builtin_amdgcn_mfma_f32_16x16x32_bf16(aq[m], bk[n], accs[m][n], 0, 0, 0);
  }

#pragma unroll
  for (int m = 0; m < 2; ++m) {
#pragma unroll
    for (int rr = 0; rr < 4; ++rr) {
      float a0 = accs[m][0][rr], a1 = accs[m][1][rr];
      float mx = fmaxf(a0, a1);
      mx = fmaxf(mx, __shfl_xor(mx, 1));
      mx = fmaxf(mx, __shfl_xor(mx, 2));
      mx = fmaxf(mx, __shfl_xor(mx, 4));
      mx = fmaxf(mx, __shfl_xor(mx, 8));
      float p0 = __expf(a0 - mx), p1 = __expf(a1 - mx);
      float sm = p0 + p1;
      sm += __shfl_xor(sm, 1);
      sm += __shfl_xor(sm, 2);
      sm += __shfl_xor(sm, 4);
      sm += __shfl_xor(sm, 8);
      const float inv = 1.0f / sm;
      const int i = 16 * m + qq * 4 + rr;
      pS[w][i * 40 + fr16]      = f2b(p0 * inv);
      pS[w][i * 40 + 16 + fr16] = f2b(p1 * inv);
    }
  }
  asm volatile("s_waitcnt lgkmcnt(0)" ::: "memory");
  __builtin_amdgcn_sched_barrier(0);

  bf16x8 ap[2], bv[4];
#pragma unroll
  for (int m = 0; m < 2; ++m)
    ap[m] = *reinterpret_cast<const bf16x8*>(&pS[w][(16 * m + fr16) * 40 + qq * 8]);
#pragma unroll
  for (int n = 0; n < 4; ++n)
    bv[n] = *reinterpret_cast<const bf16x8*>(&vTS[w][(16 * n + fr16) * 40 + qq * 8]);
  f32x4 acco[2][4] = {};
#pragma unroll
  for (int m = 0; m < 2; ++m)
#pragma unroll
    for (int n = 0; n < 4; ++n)
      acco[m][n] = __builtin_amdgcn_mfma_f32_16x16x32_bf16(ap[m], bv[n], acco[m][n], 0, 0, 0);

#pragma unroll
  for (int m = 0; m < 2; ++m) {
#pragma unroll
    for (int rr = 0; rr < 4; ++rr) {
      const int i = 16 * m + qq * 4 + rr;
      unsigned short* orow = ctx + (size_t)(b * 32 + i) * 2048 + h * 64;
#pragma unroll
      for (int n = 0; n < 4; ++n)
        orow[16 * n + fr16] = f2b(acco[m][n][rr]);
    }
  }
}

// ---------------- launch ----------------

extern "C" void kernel_launch(void* const* d_in, const int* in_sizes, int n_in,
                              void* d_out, int out_size, void* d_ws, size_t ws_size,
                              hipStream_t stream) {
  const float* x   = (const float*)d_in[0];
  const float* wq  = (const float*)d_in[1];
  const float* bq  = (const float*)d_in[2];
  const float* wk  = (const float*)d_in[3];
  const float* bk  = (const float*)d_in[4];
  const float* wv  = (const float*)d_in[5];
  const float* bv  = (const float*)d_in[6];
  const float* wo  = (const float*)d_in[7];
  const float* bo  = (const float*)d_in[8];
  const float* rpe = (const float*)d_in[9];

  char* ws = (char*)d_ws;
  unsigned short* xb    = (unsigned short*)(ws);
  unsigned short* wqkvb = (unsigned short*)(ws + 67108864);
  unsigned short* wob   = (unsigned short*)(ws + 67108864 + 25165824);
  unsigned short* qkvb  = (unsigned short*)(ws + 67108864 + 25165824 + 8388608);
  float*          bqkv  = (float*)(ws + 67108864 + 25165824 + 8388608 + 201326592);
  unsigned short* relb  = (unsigned short*)(ws + 67108864 + 25165824 + 8388608 + 201326592 + 24576);

  k_cast_f32_bf16<<<32768, 256, 0, stream>>>(x, xb, 8388608);          // 16384*2048/4
  k_build_wqkv<<<12288, 256, 0, stream>>>(wq, wk, wv, wqkvb);
  k_cast_f32_bf16<<<4096, 256, 0, stream>>>(wo, wob, 1048576);         // 2048*2048/4
  k_build_bqkv<<<24, 256, 0, stream>>>(bq, bk, bv, bqkv);
  k_build_rel<<<64, 256, 0, stream>>>(rpe, relb);

  // QKV projection: grid 64x24=1536 (%8==0)
  k_gemm256<0><<<(16384 / 256) * (6144 / 256), 512, 0, stream>>>(
      xb, wqkvb, bqkv, qkvb, 16384, 6144, 2048);

  // MFMA attention -> ctx (reuses xb buffer); 4096 blocks, wave per (b,h)
  k_attn<<<4096, 256, 0, stream>>>(qkvb, relb, xb);

  // output projection: grid 64x8=512 (%8==0)
  k_gemm256<1><<<(16384 / 256) * (2048 / 256), 512, 0, stream>>>(
      xb, wob, bo, (float*)d_out, 16384, 2048, 2048);
}